// Round 7
// baseline (1036.183 us; speedup 1.0000x reference)
//
#include <hip/hip_runtime.h>
#include <hip/hip_bf16.h>

#define DIM 1024
#define HID 2816
#define NEXP 7
#define TOKENS 8192
#define NT16 (DIM / 64)

// ---- tier-1 workspace layout (bytes); P (<=26368 x DIM fp32 = 108.0 MB) aliases Xb+WguA ----
#define MW3_XB    0ull                  // 16,777,216
#define MW3_WGU   16777216ull           // 92,274,688
#define MW3_WD    109051904ull          // 46,137,344
#define MW3_H     155189248ull          // 26368 x HID bf16 = 148,504,576
#define MW3_TOK   303693824ull          // 26368 x int
#define MW3_WGT   303799296ull          // 26368 x float
#define MW3_SLT   303904768ull          // 8192 x int2
#define MW3_META  303970304ull          // 512 ints
#define MW3_NEED  303972352ull

// ---- R2 fallback layout ----
#define MW_XB    0ull
#define MW_H     16777216ull
#define MW_WGU   114098176ull
#define MW_WD    206372864ull
#define MW_TOK   252510208ull
#define MW_WGT   252579328ull
#define MW_META  252648448ull
#define MW_NEED  252650496ull

typedef __bf16 bf16x8 __attribute__((ext_vector_type(8)));
typedef float f32x4 __attribute__((ext_vector_type(4)));

static __device__ __forceinline__ unsigned short f2b(float f) {
  union { float f; unsigned int i; } c; c.f = f;
  unsigned int i = c.i;
  unsigned int r = (i + 0x7fffu + ((i >> 16) & 1u)) >> 16;
  return (unsigned short)r;
}

// async global->LDS, 16 bytes per lane. Global addr is per-lane; LDS dest = wave base + lane*16.
static __device__ __forceinline__ void gload16(const void* g, void* l) {
  __builtin_amdgcn_global_load_lds(
      (const __attribute__((address_space(1))) unsigned int*)g,
      (__attribute__((address_space(3))) unsigned int*)l, 16, 0, 0);
}

// ---------------- router ----------------
__global__ __launch_bounds__(256, 2) void router_kernel(
    const float* __restrict__ X,
    const float* __restrict__ Wr,
    const float* __restrict__ bias,
    int* __restrict__ eidx,
    float* __restrict__ ew)
{
  __shared__ float wr[DIM * NEXP];
  for (int i = threadIdx.x; i < DIM * NEXP; i += 256) wr[i] = Wr[i];
  __syncthreads();
  int t = blockIdx.x * 256 + threadIdx.x;
  float acc[NEXP];
#pragma unroll
  for (int e = 0; e < NEXP; ++e) acc[e] = 0.f;
  const float* xp = X + (size_t)t * DIM;
  for (int d0 = 0; d0 < DIM; d0 += 4) {
    float4 xv = *(const float4*)(xp + d0);
    const float* xs = (const float*)&xv;
#pragma unroll
    for (int j = 0; j < 4; ++j) {
      float xf = xs[j];
#pragma unroll
      for (int e = 0; e < NEXP; ++e) acc[e] += xf * wr[(d0 + j) * NEXP + e];
    }
  }
  float p[NEXP];
#pragma unroll
  for (int e = 0; e < NEXP; ++e)
    p[e] = 1.f / (1.f + __expf(-acc[e] * bias[e]));
  float best = -1.f; int bi = 0;
#pragma unroll
  for (int e = 0; e < NEXP; ++e) if (p[e] > best) { best = p[e]; bi = e; }
  float sec = -1.f; int si = 0;
#pragma unroll
  for (int e = 0; e < NEXP; ++e) if (e != bi && p[e] > sec) { sec = p[e]; si = e; }
  float s = best + sec;
  eidx[t] = bi | (si << 8);
  ((float2*)ew)[t] = make_float2(best / s, sec / s);
}

// ---------------- X fp32 -> bf16 ----------------
__global__ __launch_bounds__(256) void xcvt_kernel(
    const float* __restrict__ X, unsigned short* __restrict__ Xb)
{
  int i = (blockIdx.x * 256 + threadIdx.x) * 8;
  float4 v0 = *(const float4*)&X[i];
  float4 v1 = *(const float4*)&X[i + 4];
  unsigned short o[8];
  o[0] = f2b(v0.x); o[1] = f2b(v0.y); o[2] = f2b(v0.z); o[3] = f2b(v0.w);
  o[4] = f2b(v1.x); o[5] = f2b(v1.y); o[6] = f2b(v1.z); o[7] = f2b(v1.w);
  *(int4*)&Xb[i] = *(const int4*)o;
}

// ---------------- build3: 256-padded slot lists + dual block maps ----------------
// meta[e]=count (e=0 dense), meta[8+e]=slot base (256-aligned)
// meta[16]=nblk256, meta[17]=nblk128
// meta[32+i]  = map256: e | (mb<<4)    (mb in 256-row units, expert-relative)
// meta[160+i] = map128: e | (mb<<4)    (mb in 128-row units)
__global__ __launch_bounds__(256) void build3_kernel(
    const int* __restrict__ eidx, const float* __restrict__ ew,
    int* __restrict__ tok, float* __restrict__ wgt,
    int2* __restrict__ slt, int* __restrict__ meta)
{
  __shared__ int cnt[NEXP], fill[NEXP], ofs[NEXP];
  const int tid = threadIdx.x;
  const int lane = tid & 63, wid = tid >> 6;
  if (tid < NEXP) { cnt[tid] = 0; fill[tid] = 0; }
  for (int i = tid; i < TOKENS; i += 256) { tok[i] = i; wgt[i] = 1.f; }
  __syncthreads();
  const unsigned long long lmask = (1ull << lane) - 1ull;
  for (int base = wid * 64; base < TOKENS; base += 256) {
    int t = base + lane;
    int p = eidx[t];
    int e0 = p & 0xff, e1 = (p >> 8) & 0xff;
#pragma unroll
    for (int e = 0; e < NEXP; ++e) {
      unsigned long long m0 = __ballot(e0 == e);
      unsigned long long m1 = __ballot(e1 == e);
      if (lane == 0) {
        int tot = __popcll(m0) + __popcll(m1);
        if (tot) atomicAdd(&cnt[e], tot);
      }
    }
  }
  __syncthreads();
  if (tid == 0) {
    int o = 0, nb = 0, nb2 = 0;
    meta[0] = TOKENS; meta[8] = 0;
    for (int i = 0; i < TOKENS / 256; ++i) meta[32 + nb++] = 0 | (i << 4);
    for (int i = 0; i < TOKENS / 128; ++i) meta[160 + nb2++] = 0 | (i << 4);
    for (int e = 0; e < NEXP; ++e) {
      ofs[e] = o;
      meta[1 + e] = cnt[e];
      meta[9 + e] = TOKENS + o;
      int b = (cnt[e] + 255) >> 8;
      for (int i = 0; i < b; ++i)     meta[32 + nb++]   = (e + 1) | (i << 4);
      for (int i = 0; i < 2 * b; ++i) meta[160 + nb2++] = (e + 1) | (i << 4);
      o += b << 8;
    }
    meta[16] = nb; meta[17] = nb2;
  }
  __syncthreads();
  for (int base = wid * 64; base < TOKENS; base += 256) {
    int t = base + lane;
    int p = eidx[t];
    int e0 = p & 0xff, e1 = (p >> 8) & 0xff;
    float2 w = ((const float2*)ew)[t];
    int s0 = 0, s1 = 0;
#pragma unroll
    for (int e = 0; e < NEXP; ++e) {
      unsigned long long m0 = __ballot(e0 == e);
      unsigned long long m1 = __ballot(e1 == e);
      int tot = __popcll(m0) + __popcll(m1);
      int wb = 0;
      if (lane == 0 && tot) wb = atomicAdd(&fill[e], tot);
      wb = __shfl(wb, 0);
      if (e0 == e) {
        int sl = TOKENS + ofs[e] + wb + __popcll(m0 & lmask);
        tok[sl] = t; wgt[sl] = w.x; s0 = sl;
      }
      if (e1 == e) {
        int sl = TOKENS + ofs[e] + wb + __popcll(m0) + __popcll(m1 & lmask);
        tok[sl] = t; wgt[sl] = w.y; s1 = sl;
      }
    }
    slt[t] = make_int2(s0, s1);
  }
}

// ---------------- transpose + convert, all experts ----------------
__global__ __launch_bounds__(256) void transpose_all_kernel(
    const float* __restrict__ sg, const float* __restrict__ su, const float* __restrict__ sd,
    const float* __restrict__ rg, const float* __restrict__ ru, const float* __restrict__ rd,
    unsigned short* __restrict__ WguA, unsigned short* __restrict__ WdA)
{
  int b = blockIdx.x;
  int e = b / 2112, r = b % 2112;
  int m = r / 704, q2 = r % 704;
  const float* src; unsigned short* dst; int K, N, nb, kb;
  if (m == 0) {
    src = e ? rg + (size_t)(e - 1) * DIM * HID : sg;
    dst = WguA + (size_t)e * (2 * (size_t)HID * DIM);
    K = DIM; N = HID; nb = q2 % 44; kb = q2 / 44;
  } else if (m == 1) {
    src = e ? ru + (size_t)(e - 1) * DIM * HID : su;
    dst = WguA + (size_t)e * (2 * (size_t)HID * DIM) + (size_t)HID * DIM;
    K = DIM; N = HID; nb = q2 % 44; kb = q2 / 44;
  } else {
    src = e ? rd + (size_t)(e - 1) * HID * DIM : sd;
    dst = WdA + (size_t)e * ((size_t)HID * DIM);
    K = HID; N = DIM; nb = q2 % 16; kb = q2 / 16;
  }
  __shared__ unsigned short t[64][72];
  const int n0 = nb * 64, k0 = kb * 64;
  const int tid = threadIdx.x;
  const int kl = tid >> 4, nl = (tid & 15) * 4;
#pragma unroll
  for (int i = 0; i < 4; ++i) {
    int k = kl + i * 16;
    float4 v = *(const float4*)&src[(size_t)(k0 + k) * N + n0 + nl];
    t[nl + 0][k] = f2b(v.x); t[nl + 1][k] = f2b(v.y);
    t[nl + 2][k] = f2b(v.z); t[nl + 3][k] = f2b(v.w);
  }
  __syncthreads();
  const int nl2 = tid >> 3, kc = (tid & 7) * 8;
#pragma unroll
  for (int i = 0; i < 2; ++i) {
    int n = nl2 + i * 32;
    *(int4*)&dst[(size_t)(n0 + n) * K + k0 + kc] = *(const int4*)&t[n][kc];
  }
}

// ======== gateup8: 8-wave, triple-buffered, counted-vmcnt phase schedule (T3+T4+T5) ========
// BM=256 BN=64 BK=64. 2 phases per K-tile (gate, up), 16 MFMA/wave/phase.
// Loads for tile t+2 issued during tile t (3/phase); vmcnt(6) once per tile validates t+1.
// Granule-XOR LDS swizzle carried from the proven kernels (pre-swizzled global source).
__global__ __launch_bounds__(512, 2) void gateup8_kernel(
    const unsigned short* __restrict__ Xb,
    const unsigned short* __restrict__ WguA,
    const int* __restrict__ tok, const float* __restrict__ wgt,
    const int* __restrict__ meta,
    unsigned short* __restrict__ H)
{
  const int yb = blockIdx.y;
  if (yb >= meta[16]) return;
  const int ent = meta[32 + yb];
  const int e = ent & 15, mb = ent >> 4;
  const int cnt = meta[e];
  const int pofs = meta[8 + e];
  const int m0 = mb * 256;
  const unsigned short* Wg = WguA + (size_t)e * (2 * (size_t)HID * DIM);
  const unsigned short* Wu = Wg + (size_t)HID * DIM;

  __shared__ __align__(16) unsigned short As[3][256 * 64];   // 96 KB
  __shared__ __align__(16) unsigned short Bgs[3][64 * 64];   // 24 KB
  __shared__ __align__(16) unsigned short Bus[3][64 * 64];   // 24 KB
  __shared__ float wl[256];

  const int tid = threadIdx.x;
  const int lane = tid & 63;
  const int w = tid >> 6;
  const int wmi = w & 3;        // M strip (64 rows)
  const int wni = w >> 2;       // N strip (32 cols)
  const int c = lane & 15;
  const int q = lane >> 4;
  const int cx = c & 7;

  const int srow = tid >> 3;                       // 0..63
  const int swz = ((tid & 7) ^ (srow & 7)) * 8;    // pre-swizzled source granule

  const unsigned short* aptr[4];
#pragma unroll
  for (int i = 0; i < 4; ++i) {
    int s = m0 + i * 64 + srow;
    int t = (s < cnt) ? tok[pofs + s] : 0;
    aptr[i] = Xb + (size_t)t * DIM + swz;
  }
  const int n0 = blockIdx.x * 64;
  const unsigned short* gptr = Wg + (size_t)(n0 + srow) * DIM + swz;
  const unsigned short* uptr = Wu + (size_t)(n0 + srow) * DIM + swz;

  if (tid < 256) wl[tid] = (m0 + tid < cnt) ? wgt[pofs + m0 + tid] : 0.f;

  // prologue: stage tiles 0 and 1, full drain
#pragma unroll
  for (int t = 0; t < 2; ++t) {
#pragma unroll
    for (int i = 0; i < 4; ++i) gload16(aptr[i] + t * 64, &As[t][i * 4096 + tid * 8]);
    gload16(gptr + t * 64, &Bgs[t][tid * 8]);
    gload16(uptr + t * 64, &Bus[t][tid * 8]);
  }
  __syncthreads();

  f32x4 accg[4][2], accu[4][2];
#pragma unroll
  for (int mi = 0; mi < 4; ++mi)
#pragma unroll
    for (int ni = 0; ni < 2; ++ni) {
      accg[mi][ni] = {0.f, 0.f, 0.f, 0.f};
      accu[mi][ni] = {0.f, 0.f, 0.f, 0.f};
    }

  int b = 0, bs = 2;
#pragma unroll 1
  for (int t = 0; t < NT16; ++t) {
    // ---- phase 0: gate ----
    bf16x8 a[4][2], bg[2][2];
#pragma unroll
    for (int mi = 0; mi < 4; ++mi)
#pragma unroll
      for (int ks = 0; ks < 2; ++ks)
        a[mi][ks] = *(const bf16x8*)&As[b][(wmi * 64 + mi * 16 + c) * 64 + (((ks * 4 + q) ^ cx) * 8)];
#pragma unroll
    for (int ni = 0; ni < 2; ++ni)
#pragma unroll
      for (int ks = 0; ks < 2; ++ks)
        bg[ni][ks] = *(const bf16x8*)&Bgs[b][(wni * 32 + ni * 16 + c) * 64 + (((ks * 4 + q) ^ cx) * 8)];
    if (t + 2 < NT16) {
      const int k2 = (t + 2) * 64;
      gload16(aptr[0] + k2, &As[bs][0 * 4096 + tid * 8]);
      gload16(aptr[1] + k2, &As[bs][1 * 4096 + tid * 8]);
      gload16(aptr[2] + k2, &As[bs][2 * 4096 + tid * 8]);
    }
    __builtin_amdgcn_s_barrier();
    asm volatile("s_waitcnt lgkmcnt(0)" ::: "memory");
    __builtin_amdgcn_sched_barrier(0);
    __builtin_amdgcn_s_setprio(1);
#pragma unroll
    for (int mi = 0; mi < 4; ++mi)
#pragma unroll
      for (int ni = 0; ni < 2; ++ni) {
        accg[mi][ni] = __builtin_amdgcn_mfma_f32_16x16x32_bf16(a[mi][0], bg[ni][0], accg[mi][ni], 0, 0, 0);
        accg[mi][ni] = __builtin_amdgcn_mfma_f32_16x16x32_bf16(a[mi][1], bg[ni][1], accg[mi][ni], 0, 0, 0);
      }
    __builtin_amdgcn_s_setprio(0);
    __builtin_amdgcn_sched_barrier(0);
    __builtin_amdgcn_s_barrier();
    __builtin_amdgcn_sched_barrier(0);

    // ---- phase 1: up ----
    bf16x8 bu[2][2];
#pragma unroll
    for (int ni = 0; ni < 2; ++ni)
#pragma unroll
      for (int ks = 0; ks < 2; ++ks)
        bu[ni][ks] = *(const bf16x8*)&Bus[b][(wni * 32 + ni * 16 + c) * 64 + (((ks * 4 + q) ^ cx) * 8)];
    if (t + 2 < NT16) {
      const int k2 = (t + 2) * 64;
      gload16(aptr[3] + k2, &As[bs][3 * 4096 + tid * 8]);
      gload16(gptr + k2, &Bgs[bs][tid * 8]);
      gload16(uptr + k2, &Bus[bs][tid * 8]);
      asm volatile("s_waitcnt vmcnt(6)" ::: "memory");   // t+1's loads complete; t+2's may fly
    } else if (t + 1 < NT16) {
      asm volatile("s_waitcnt vmcnt(0)" ::: "memory");   // drain for last tile
    }
    __builtin_amdgcn_s_barrier();
    asm volatile("s_waitcnt lgkmcnt(0)" ::: "memory");
    __builtin_amdgcn_sched_barrier(0);
    __builtin_amdgcn_s_setprio(1);
#pragma unroll
    for (int mi = 0; mi < 4; ++mi)
#pragma unroll
      for (int ni = 0; ni < 2; ++ni) {
        accu[mi][ni] = __builtin_amdgcn_mfma_f32_16x16x32_bf16(a[mi][0], bu[ni][0], accu[mi][ni], 0, 0, 0);
        accu[mi][ni] = __builtin_amdgcn_mfma_f32_16x16x32_bf16(a[mi][1], bu[ni][1], accu[mi][ni], 0, 0, 0);
      }
    __builtin_amdgcn_s_setprio(0);
    __builtin_amdgcn_sched_barrier(0);
    __builtin_amdgcn_s_barrier();
    __builtin_amdgcn_sched_barrier(0);

    b = (b == 2) ? 0 : b + 1;
    bs = (bs == 2) ? 0 : bs + 1;
  }

#pragma unroll
  for (int mi = 0; mi < 4; ++mi)
#pragma unroll
    for (int ni = 0; ni < 2; ++ni)
#pragma unroll
      for (int r = 0; r < 4; ++r) {
        int row = wmi * 64 + mi * 16 + q * 4 + r;
        int col = wni * 32 + ni * 16 + c;
        float g = accg[mi][ni][r];
        float u = accu[mi][ni][r];
        float h = (g / (1.f + __expf(-g))) * u * wl[row];
        H[(size_t)(pofs + m0 + row) * HID + n0 + col] = f2b(h);
      }
}

// ---------------- unified down: all slots, clean partial writes (proven R6 structure) ----------------
__global__ __launch_bounds__(256, 2) void down_all_kernel(
    const unsigned short* __restrict__ Hm,
    const unsigned short* __restrict__ WdA,
    const int* __restrict__ meta,
    float* __restrict__ P)
{
  const int yb = blockIdx.y;
  if (yb >= meta[17]) return;
  const int ent = meta[160 + yb];
  const int e = ent & 15, mb = ent >> 4;
  const int pofs = meta[8 + e];
  const unsigned short* WdT = WdA + (size_t)e * ((size_t)HID * DIM);

  __shared__ __align__(16) unsigned short As[128 * 64];
  __shared__ __align__(16) unsigned short Bs[128 * 64];
  const int n0 = blockIdx.x * 128;
  const int tid = threadIdx.x;
  const int lane = tid & 63;
  const int w4 = tid >> 6;
  const int wm = (w4 & 1) * 64;
  const int wn = (w4 >> 1) * 64;
  const int c = lane & 15;
  const int q = lane >> 4;
  const int cx = c & 7;

  const int r8 = lane >> 3;
  const int swz = ((lane & 7) ^ r8) * 8;
  const int wrow = w4 * 8 + r8;

  const unsigned short* aptr[4];
  const unsigned short* bptr[4];
#pragma unroll
  for (int i = 0; i < 4; ++i) {
    aptr[i] = Hm + (size_t)(pofs + mb * 128 + i * 32 + wrow) * HID + swz;
    bptr[i] = WdT + (size_t)(n0 + i * 32 + wrow) * HID + swz;
  }

  f32x4 acc[4][4];
#pragma unroll
  for (int mi = 0; mi < 4; ++mi)
#pragma unroll
    for (int ni = 0; ni < 4; ++ni) acc[mi][ni] = {0.f, 0.f, 0.f, 0.f};

  for (int k0 = 0; k0 < HID; k0 += 64) {
    __syncthreads();
#pragma unroll
    for (int i = 0; i < 4; ++i) {
      gload16(aptr[i] + k0, &As[i * 2048 + tid * 8]);
      gload16(bptr[i] + k0, &Bs[i * 2048 + tid * 8]);
    }
    __syncthreads();
#pragma unroll
    for (int h = 0; h < 2; ++h) {
      const int go = ((h * 4 + q) ^ cx) * 8;
      bf16x8 a[4], bb[4];
#pragma unroll
      for (int mi = 0; mi < 4; ++mi)
        a[mi] = *(const bf16x8*)&As[(wm + mi * 16 + c) * 64 + go];
#pragma unroll
      for (int ni = 0; ni < 4; ++ni)
        bb[ni] = *(const bf16x8*)&Bs[(wn + ni * 16 + c) * 64 + go];
#pragma unroll
      for (int mi = 0; mi < 4; ++mi)
#pragma unroll
        for (int ni = 0; ni < 4; ++ni)
          acc[mi][ni] = __builtin_amdgcn_mfma_f32_16x16x32_bf16(a[mi], bb[ni], acc[mi][ni], 0, 0, 0);
    }
  }
#pragma unroll
  for (int mi = 0; mi < 4; ++mi)
#pragma unroll
    for (int r = 0; r < 4; ++r) {
      int prow = pofs + mb * 128 + wm + mi * 16 + q * 4 + r;
#pragma unroll
      for (int ni = 0; ni < 4; ++ni) {
        int col = n0 + wn + ni * 16 + c;
        P[(size_t)prow * DIM + col] = acc[mi][ni][r];
      }
    }
}

// ---------------- combine: out[t] = P[t] + P[s0[t]] + P[s1[t]] ----------------
__global__ __launch_bounds__(256) void combine_kernel(
    const float* __restrict__ P, const int2* __restrict__ slt,
    float* __restrict__ out)
{
  const int t = blockIdx.x;
  const int2 s = slt[t];
  const int d = threadIdx.x;
  float4 a = ((const float4*)(P + (size_t)t * DIM))[d];
  float4 b = ((const float4*)(P + (size_t)s.x * DIM))[d];
  float4 cc = ((const float4*)(P + (size_t)s.y * DIM))[d];
  float4 o;
  o.x = a.x + b.x + cc.x; o.y = a.y + b.y + cc.y;
  o.z = a.z + b.z + cc.z; o.w = a.w + b.w + cc.w;
  ((float4*)(out + (size_t)t * DIM))[d] = o;
}

// ================= R2 fallback kernels (proven path, used if ws too small) =================
__global__ __launch_bounds__(256) void build_kernel(
    const int* __restrict__ eidx, const float* __restrict__ ew,
    int* __restrict__ tok, float* __restrict__ wgt, int* __restrict__ meta,
    int padmode)
{
  __shared__ int cnt[NEXP], fill[NEXP], ofs[NEXP];
  if (threadIdx.x < NEXP) { cnt[threadIdx.x] = 0; fill[threadIdx.x] = 0; }
  __syncthreads();
  for (int t = threadIdx.x; t < TOKENS; t += 256) {
    int p = eidx[t];
    atomicAdd(&cnt[p & 0xff], 1);
    atomicAdd(&cnt[(p >> 8) & 0xff], 1);
  }
  __syncthreads();
  if (threadIdx.x == 0) {
    int o = 0, nb = 0;
    for (int e = 0; e < NEXP; ++e) {
      ofs[e] = o;
      meta[e] = cnt[e];
      meta[8 + e] = o;
      if (padmode) {
        int b = (cnt[e] + 127) >> 7;
        for (int i = 0; i < b; ++i) meta[16 + nb++] = e | (i << 3);
        o += b << 7;
      } else {
        o += cnt[e];
      }
    }
    meta[15] = nb;
  }
  __syncthreads();
  for (int t = threadIdx.x; t < TOKENS; t += 256) {
    int p = eidx[t];
    int e0 = p & 0xff, e1 = (p >> 8) & 0xff;
    float2 w = ((const float2*)ew)[t];
    int p0 = ofs[e0] + atomicAdd(&fill[e0], 1);
    tok[p0] = t; wgt[p0] = w.x;
    int p1 = ofs[e1] + atomicAdd(&fill[e1], 1);
    tok[p1] = t; wgt[p1] = w.y;
  }
}

__global__ __launch_bounds__(256, 2) void gateup_kernel(
    const unsigned short* __restrict__ Xb,
    const unsigned short* __restrict__ Wgu,
    unsigned short* __restrict__ H)
{
  __shared__ __align__(16) unsigned short As[128 * 64];
  __shared__ __align__(16) unsigned short Bgs[64 * 64];
  __shared__ __align__(16) unsigned short Bus[64 * 64];
  const int m0 = blockIdx.y * 128;
  const int n0 = blockIdx.x * 64;
  const int tid = threadIdx.x;
  const int lane = tid & 63;
  const int w = tid >> 6;
  const int wm = (w & 1) * 64;
  const int wn = (w >> 1) * 32;
  const int c = lane & 15;
  const int q = lane >> 4;
  const int cx = c & 7;
  const unsigned short* Wg = Wgu;
  const unsigned short* Wu = Wgu + (size_t)HID * DIM;
  const int r8 = lane >> 3;
  const int swz = ((lane & 7) ^ r8) * 8;
  const int wrow = w * 8 + r8;
  const unsigned short* aptr[4];
#pragma unroll
  for (int i = 0; i < 4; ++i)
    aptr[i] = Xb + (size_t)(m0 + i * 32 + wrow) * DIM + swz;
  const unsigned short* gptr[2];
  const unsigned short* uptr[2];
#pragma unroll
  for (int i = 0; i < 2; ++i) {
    gptr[i] = Wg + (size_t)(n0 + i * 32 + wrow) * DIM + swz;
    uptr[i] = Wu + (size_t)(n0 + i * 32 + wrow) * DIM + swz;
  }
  f32x4 accg[4][2], accu[4][2];
#pragma unroll
  for (int mi = 0; mi < 4; ++mi)
#pragma unroll
    for (int ni = 0; ni < 2; ++ni) {
      accg[mi][ni] = {0.f, 0.f, 0.f, 0.f};
      accu[mi][ni] = {0.f, 0.f, 0.f, 0.f};
    }
  for (int k0 = 0; k0 < DIM; k0 += 64) {
    __syncthreads();
#pragma unroll
    for (int i = 0; i < 4; ++i) gload16(aptr[i] + k0, &As[i * 2048 + tid * 8]);
#pragma unroll
    for (int i = 0; i < 2; ++i) {
      gload16(gptr[i] + k0, &Bgs[i * 2048 + tid * 8]);
      gload16(uptr[i] + k0, &Bus[i * 2048 + tid * 8]);
    }
    __syncthreads();
#pragma unroll
    for (int h = 0; h < 2; ++h) {
      const int go = ((h * 4 + q) ^ cx) * 8;
      bf16x8 a[4], bg[2], bu[2];
#pragma unroll
      for (int mi = 0; mi < 4; ++mi)
        a[mi] = *(const bf16x8*)&As[(wm + mi * 16 + c) * 64 + go];
#pragma unroll
      for (int ni = 0; ni < 2; ++ni) {
        bg[ni] = *(const bf16x8*)&Bgs[(wn + ni * 16 + c) * 64 + go];
        bu[ni] = *(const bf16x8*)&Bus[(wn + ni * 16 + c) * 64 + go];
      }
#pragma unroll
      for (int mi = 0; mi < 4; ++mi)
#pragma unroll
        for (int ni = 0; ni < 2; ++ni) {
          accg[mi][ni] = __builtin_amdgcn_mfma_f32_16x16x32_bf16(a[mi], bg[ni], accg[mi][ni], 0, 0, 0);
          accu[mi][ni] = __builtin_amdgcn_mfma_f32_16x16x32_bf16(a[mi], bu[ni], accu[mi][ni], 0, 0, 0);
        }
    }
  }
#pragma unroll
  for (int mi = 0; mi < 4; ++mi)
#pragma unroll
    for (int ni = 0; ni < 2; ++ni)
#pragma unroll
      for (int r = 0; r < 4; ++r) {
        int row = wm + mi * 16 + q * 4 + r;
        int col = wn + ni * 16 + c;
        float g = accg[mi][ni][r];
        float u = accu[mi][ni][r];
        float h = (g / (1.f + __expf(-g))) * u;
        H[(size_t)(m0 + row) * HID + n0 + col] = f2b(h);
      }
}

__global__ __launch_bounds__(256, 2) void gateup_sparse_all_kernel(
    const unsigned short* __restrict__ Xb,
    const unsigned short* __restrict__ WguR,
    const int* __restrict__ tok, const float* __restrict__ wgt,
    const int* __restrict__ meta,
    unsigned short* __restrict__ H)
{
  const int yb = blockIdx.y;
  if (yb >= meta[15]) return;
  const int bm = meta[16 + yb];
  const int e = bm & 7, mb = bm >> 3;
  const int cnt = meta[e];
  const int pofs = meta[8 + e];
  const unsigned short* Wgu = WguR + (size_t)e * (2 * (size_t)HID * DIM);
  __shared__ __align__(16) unsigned short As[128 * 64];
  __shared__ __align__(16) unsigned short Bgs[64 * 64];
  __shared__ __align__(16) unsigned short Bus[64 * 64];
  __shared__ float wl[128];
  const int n0 = blockIdx.x * 64;
  const int tid = threadIdx.x;
  const int lane = tid & 63;
  const int w = tid >> 6;
  const int wm = (w & 1) * 64;
  const int wn = (w >> 1) * 32;
  const int c = lane & 15;
  const int q = lane >> 4;
  const int cx = c & 7;
  if (tid < 128)
    wl[tid] = (mb * 128 + tid < cnt) ? wgt[pofs + mb * 128 + tid] : 0.f;
  const unsigned short* Wg = Wgu;
  const unsigned short* Wu = Wgu + (size_t)HID * DIM;
  const int r8 = lane >> 3;
  const int swz = ((lane & 7) ^ r8) * 8;
  const int wrow = w * 8 + r8;
  const unsigned short* aptr[4];
#pragma unroll
  for (int i = 0; i < 4; ++i) {
    int s = mb * 128 + i * 32 + wrow;
    int t = (s < cnt) ? tok[pofs + s] : 0;
    aptr[i] = Xb + (size_t)t * DIM + swz;
  }
  const unsigned short* gptr[2];
  const unsigned short* uptr[2];
#pragma unroll
  for (int i = 0; i < 2; ++i) {
    gptr[i] = Wg + (size_t)(n0 + i * 32 + wrow) * DIM + swz;
    uptr[i] = Wu + (size_t)(n0 + i * 32 + wrow) * DIM + swz;
  }
  f32x4 accg[4][2], accu[4][2];
#pragma unroll
  for (int mi = 0; mi < 4; ++mi)
#pragma unroll
    for (int ni = 0; ni < 2; ++ni) {
      accg[mi][ni] = {0.f, 0.f, 0.f, 0.f};
      accu[mi][ni] = {0.f, 0.f, 0.f, 0.f};
    }
  for (int k0 = 0; k0 < DIM; k0 += 64) {
    __syncthreads();
#pragma unroll
    for (int i = 0; i < 4; ++i) gload16(aptr[i] + k0, &As[i * 2048 + tid * 8]);
#pragma unroll
    for (int i = 0; i < 2; ++i) {
      gload16(gptr[i] + k0, &Bgs[i * 2048 + tid * 8]);
      gload16(uptr[i] + k0, &Bus[i * 2048 + tid * 8]);
    }
    __syncthreads();
#pragma unroll
    for (int h = 0; h < 2; ++h) {
      const int go = ((h * 4 + q) ^ cx) * 8;
      bf16x8 a[4], bg[2], bu[2];
#pragma unroll
      for (int mi = 0; mi < 4; ++mi)
        a[mi] = *(const bf16x8*)&As[(wm + mi * 16 + c) * 64 + go];
#pragma unroll
      for (int ni = 0; ni < 2; ++ni) {
        bg[ni] = *(const bf16x8*)&Bgs[(wn + ni * 16 + c) * 64 + go];
        bu[ni] = *(const bf16x8*)&Bus[(wn + ni * 16 + c) * 64 + go];
      }
#pragma unroll
      for (int mi = 0; mi < 4; ++mi)
#pragma unroll
        for (int ni = 0; ni < 2; ++ni) {
          accg[mi][ni] = __builtin_amdgcn_mfma_f32_16x16x32_bf16(a[mi], bg[ni], accg[mi][ni], 0, 0, 0);
          accu[mi][ni] = __builtin_amdgcn_mfma_f32_16x16x32_bf16(a[mi], bu[ni], accu[mi][ni], 0, 0, 0);
        }
    }
  }
#pragma unroll
  for (int mi = 0; mi < 4; ++mi)
#pragma unroll
    for (int ni = 0; ni < 2; ++ni)
#pragma unroll
      for (int r = 0; r < 4; ++r) {
        int row = wm + mi * 16 + q * 4 + r;
        int col = wn + ni * 16 + c;
        float g = accg[mi][ni][r];
        float u = accu[mi][ni][r];
        float h = (g / (1.f + __expf(-g))) * u * wl[row];
        H[(size_t)(pofs + mb * 128 + row) * HID + n0 + col] = f2b(h);
      }
}

__global__ __launch_bounds__(256, 2) void down_dense_kernel(
    const unsigned short* __restrict__ Hm,
    const unsigned short* __restrict__ WdT,
    float* __restrict__ out)
{
  __shared__ __align__(16) unsigned short As[128 * 64];
  __shared__ __align__(16) unsigned short Bs[128 * 64];
  const int m0 = blockIdx.y * 128;
  const int n0 = blockIdx.x * 128;
  const int tid = threadIdx.x;
  const int lane = tid & 63;
  const int w4 = tid >> 6;
  const int wm = (w4 & 1) * 64;
  const int wn = (w4 >> 1) * 64;
  const int c = lane & 15;
  const int q = lane >> 4;
  const int cx = c & 7;
  const int r8 = lane >> 3;
  const int swz = ((lane & 7) ^ r8) * 8;
  const int wrow = w4 * 8 + r8;
  const unsigned short* aptr[4];
  const unsigned short* bptr[4];
#pragma unroll
  for (int i = 0; i < 4; ++i) {
    aptr[i] = Hm + (size_t)(m0 + i * 32 + wrow) * HID + swz;
    bptr[i] = WdT + (size_t)(n0 + i * 32 + wrow) * HID + swz;
  }
  f32x4 acc[4][4];
#pragma unroll
  for (int mi = 0; mi < 4; ++mi)
#pragma unroll
    for (int ni = 0; ni < 4; ++ni) acc[mi][ni] = {0.f, 0.f, 0.f, 0.f};
  for (int k0 = 0; k0 < HID; k0 += 64) {
    __syncthreads();
#pragma unroll
    for (int i = 0; i < 4; ++i) {
      gload16(aptr[i] + k0, &As[i * 2048 + tid * 8]);
      gload16(bptr[i] + k0, &Bs[i * 2048 + tid * 8]);
    }
    __syncthreads();
#pragma unroll
    for (int h = 0; h < 2; ++h) {
      const int go = ((h * 4 + q) ^ cx) * 8;
      bf16x8 a[4], bb[4];
#pragma unroll
      for (int mi = 0; mi < 4; ++mi)
        a[mi] = *(const bf16x8*)&As[(wm + mi * 16 + c) * 64 + go];
#pragma unroll
      for (int ni = 0; ni < 4; ++ni)
        bb[ni] = *(const bf16x8*)&Bs[(wn + ni * 16 + c) * 64 + go];
#pragma unroll
      for (int mi = 0; mi < 4; ++mi)
#pragma unroll
        for (int ni = 0; ni < 4; ++ni)
          acc[mi][ni] = __builtin_amdgcn_mfma_f32_16x16x32_bf16(a[mi], bb[ni], acc[mi][ni], 0, 0, 0);
    }
  }
#pragma unroll
  for (int mi = 0; mi < 4; ++mi)
#pragma unroll
    for (int r = 0; r < 4; ++r) {
      int trow = m0 + wm + mi * 16 + q * 4 + r;
#pragma unroll
      for (int ni = 0; ni < 4; ++ni) {
        int col = n0 + wn + ni * 16 + c;
        out[(size_t)trow * DIM + col] = acc[mi][ni][r];
      }
    }
}

__global__ __launch_bounds__(256, 2) void down_sparse_all_kernel(
    const unsigned short* __restrict__ Hm,
    const unsigned short* __restrict__ WdR,
    const int* __restrict__ tok, const int* __restrict__ meta,
    float* __restrict__ out)
{
  const int yb = blockIdx.y;
  if (yb >= meta[15]) return;
  const int bm = meta[16 + yb];
  const int e = bm & 7, mb = bm >> 3;
  const int cnt = meta[e];
  const int pofs = meta[8 + e];
  const unsigned short* WdT = WdR + (size_t)e * ((size_t)HID * DIM);
  const int kbase = blockIdx.z * (HID / 2);
  __shared__ __align__(16) unsigned short As[128 * 64];
  __shared__ __align__(16) unsigned short Bs[128 * 64];
  __shared__ int tl[128];
  const int n0 = blockIdx.x * 128;
  const int tid = threadIdx.x;
  const int lane = tid & 63;
  const int w4 = tid >> 6;
  const int wm = (w4 & 1) * 64;
  const int wn = (w4 >> 1) * 64;
  const int c = lane & 15;
  const int q = lane >> 4;
  const int cx = c & 7;
  if (tid < 128)
    tl[tid] = (mb * 128 + tid < cnt) ? tok[pofs + mb * 128 + tid] : 0;
  const int r8 = lane >> 3;
  const int swz = ((lane & 7) ^ r8) * 8;
  const int wrow = w4 * 8 + r8;
  const unsigned short* aptr[4];
  const unsigned short* bptr[4];
#pragma unroll
  for (int i = 0; i < 4; ++i) {
    aptr[i] = Hm + (size_t)(mb * 128 + i * 32 + wrow) * HID + kbase + swz;
    bptr[i] = WdT + (size_t)(n0 + i * 32 + wrow) * HID + kbase + swz;
  }
  f32x4 acc[4][4];
#pragma unroll
  for (int mi = 0; mi < 4; ++mi)
#pragma unroll
    for (int ni = 0; ni < 4; ++ni) acc[mi][ni] = {0.f, 0.f, 0.f, 0.f};
  for (int k0 = 0; k0 < HID / 2; k0 += 64) {
    __syncthreads();
#pragma unroll
    for (int i = 0; i < 4; ++i) {
      gload16(aptr[i] + k0, &As[i * 2048 + tid * 8]);
      gload16(bptr[i] + k0, &Bs[i * 2048 + tid * 8]);
    }
    __syncthreads();
#pragma unroll
    for (int h = 0; h < 2; ++h) {
      const int go = ((h * 4 + q) ^ cx) * 8;
      bf16x8 a[4], bb[4];
#pragma unroll
      for (int mi = 0; mi < 4; ++mi)
        a[mi] = *(const bf16x8*)&As[(wm + mi * 16 + c) * 64 + go];
#pragma unroll
      for (int ni = 0; ni < 4; ++ni)
        bb[ni] = *(const bf16x8*)&Bs[(wn + ni * 16 + c) * 64 + go];
#pragma unroll
      for (int mi = 0; mi < 4; ++mi)
#pragma unroll
        for (int ni = 0; ni < 4; ++ni)
          acc[mi][ni] = __builtin_amdgcn_mfma_f32_16x16x32_bf16(a[mi], bb[ni], acc[mi][ni], 0, 0, 0);
    }
  }
#pragma unroll
  for (int mi = 0; mi < 4; ++mi)
#pragma unroll
    for (int r = 0; r < 4; ++r) {
      int lr = wm + mi * 16 + q * 4 + r;
      if (mb * 128 + lr < cnt) {
        int t = tl[lr];
#pragma unroll
        for (int ni = 0; ni < 4; ++ni) {
          int col = n0 + wn + ni * 16 + c;
          atomicAdd(&out[(size_t)t * DIM + col], acc[mi][ni][r]);
        }
      }
    }
}

extern "C" void kernel_launch(void* const* d_in, const int* in_sizes, int n_in,
                              void* d_out, int out_size, void* d_ws, size_t ws_size,
                              hipStream_t stream) {
  (void)in_sizes; (void)n_in; (void)out_size;
  const float* x   = (const float*)d_in[0];
  const float* sg  = (const float*)d_in[1];
  const float* su  = (const float*)d_in[2];
  const float* sd  = (const float*)d_in[3];
  const float* rg  = (const float*)d_in[4];
  const float* ru  = (const float*)d_in[5];
  const float* rd  = (const float*)d_in[6];
  const float* wrr = (const float*)d_in[7];
  const float* rb  = (const float*)d_in[8];
  float* out = (float*)d_out;

  char* ws = (char*)d_ws;
  dim3 blk(256);

  if (ws_size >= MW3_NEED) {
    // -------- tier-1: unified schedule with 8-phase gateup --------
    unsigned short* Xb   = (unsigned short*)(ws + MW3_XB);
    unsigned short* WguA = (unsigned short*)(ws + MW3_WGU);
    unsigned short* WdA  = (unsigned short*)(ws + MW3_WD);
    unsigned short* H    = (unsigned short*)(ws + MW3_H);
    int*   tok           = (int*)(ws + MW3_TOK);
    float* wgt           = (float*)(ws + MW3_WGT);
    int2*  slt           = (int2*)(ws + MW3_SLT);
    int*   meta          = (int*)(ws + MW3_META);
    float* P             = (float*)ws;           // aliases Xb+WguA (dead after gateup8)
    int*   eidx = (int*)H;                       // parked in H, consumed by build
    float* ew   = (float*)((char*)H + 32768);

    router_kernel<<<dim3(TOKENS / 256), blk, 0, stream>>>(x, wrr, rb, eidx, ew);
    xcvt_kernel<<<dim3(TOKENS * DIM / (8 * 256)), blk, 0, stream>>>(x, Xb);
    build3_kernel<<<dim3(1), blk, 0, stream>>>(eidx, ew, tok, wgt, slt, meta);
    transpose_all_kernel<<<dim3(8 * 2112), blk, 0, stream>>>(sg, su, sd, rg, ru, rd, WguA, WdA);
    gateup8_kernel<<<dim3(HID / 64, 104), dim3(512), 0, stream>>>(Xb, WguA, tok, wgt, meta, H);
    down_all_kernel<<<dim3(DIM / 128, 208), blk, 0, stream>>>(H, WdA, meta, P);
    combine_kernel<<<dim3(TOKENS), blk, 0, stream>>>(P, slt, out);
  } else {
    // -------- fallback: proven R2 merged schedule --------
    unsigned short* Xb   = (unsigned short*)(ws + MW_XB);
    unsigned short* H    = (unsigned short*)(ws + MW_H);
    unsigned short* WguA = (unsigned short*)(ws + MW_WGU);
    unsigned short* WdA  = (unsigned short*)(ws + MW_WD);
    int*   tok           = (int*)(ws + MW_TOK);
    float* wgt           = (float*)(ws + MW_WGT);
    int*   meta          = (int*)(ws + MW_META);
    int*   eidx = (int*)H;
    float* ew   = (float*)((char*)H + 32768);

    router_kernel<<<dim3(TOKENS / 256), blk, 0, stream>>>(x, wrr, rb, eidx, ew);
    xcvt_kernel<<<dim3(TOKENS * DIM / (8 * 256)), blk, 0, stream>>>(x, Xb);
    build_kernel<<<dim3(1), blk, 0, stream>>>(eidx, ew, tok, wgt, meta, 1);
    transpose_all_kernel<<<dim3(8 * 2112), blk, 0, stream>>>(sg, su, sd, rg, ru, rd, WguA, WdA);
    gateup_kernel<<<dim3(HID / 64, TOKENS / 128), blk, 0, stream>>>(Xb, WguA, H);
    down_dense_kernel<<<dim3(DIM / 128, TOKENS / 128), blk, 0, stream>>>(H, WdA, out);
    const unsigned short* WguRt = WguA + 2 * (size_t)HID * DIM;
    const unsigned short* WdRt  = WdA + (size_t)HID * DIM;
    gateup_sparse_all_kernel<<<dim3(HID / 64, 135), blk, 0, stream>>>(Xb, WguRt, tok, wgt, meta, H);
    down_sparse_all_kernel<<<dim3(DIM / 128, 135, 2), blk, 0, stream>>>(H, WdRt, tok, meta, out);
  }
}

// Round 8
// 999.108 us; speedup vs baseline: 1.0371x; 1.0371x over previous
//
#include <hip/hip_runtime.h>
#include <hip/hip_bf16.h>

#define DIM 1024
#define HID 2816
#define NEXP 7
#define TOKENS 8192

// ---- tier-1 workspace layout (bytes) ----
#define MW3_XB    0ull                  // 16,777,216
#define MW3_WGU   16777216ull           // 92,274,688
#define MW3_WD    109051904ull          // 46,137,344
#define MW3_H     155189248ull          // 26368 x HID bf16 = 148,504,576
#define MW3_TOK   303693824ull          // 26368 x int
#define MW3_WGT   303799296ull          // 26368 x float
#define MW3_SLT   303904768ull          // (unused, reserved)
#define MW3_META  303970304ull          // 512 ints
#define MW3_NEED  303972352ull

// ---- R2 fallback layout ----
#define MW_XB    0ull
#define MW_H     16777216ull
#define MW_WGU   114098176ull
#define MW_WD    206372864ull
#define MW_TOK   252510208ull
#define MW_WGT   252579328ull
#define MW_META  252648448ull
#define MW_NEED  252650496ull

typedef __bf16 bf16x8 __attribute__((ext_vector_type(8)));
typedef float f32x4 __attribute__((ext_vector_type(4)));

static __device__ __forceinline__ unsigned short f2b(float f) {
  union { float f; unsigned int i; } c; c.f = f;
  unsigned int i = c.i;
  unsigned int r = (i + 0x7fffu + ((i >> 16) & 1u)) >> 16;
  return (unsigned short)r;
}

// async global->LDS, 16 bytes per lane. Global addr is per-lane; LDS dest = wave base + lane*16.
static __device__ __forceinline__ void gload16(const void* g, void* l) {
  __builtin_amdgcn_global_load_lds(
      (const __attribute__((address_space(1))) unsigned int*)g,
      (__attribute__((address_space(3))) unsigned int*)l, 16, 0, 0);
}

// ---------------- router ----------------
__global__ __launch_bounds__(256, 2) void router_kernel(
    const float* __restrict__ X,
    const float* __restrict__ Wr,
    const float* __restrict__ bias,
    int* __restrict__ eidx,
    float* __restrict__ ew)
{
  __shared__ float wr[DIM * NEXP];
  for (int i = threadIdx.x; i < DIM * NEXP; i += 256) wr[i] = Wr[i];
  __syncthreads();
  int t = blockIdx.x * 256 + threadIdx.x;
  float acc[NEXP];
#pragma unroll
  for (int e = 0; e < NEXP; ++e) acc[e] = 0.f;
  const float* xp = X + (size_t)t * DIM;
  for (int d0 = 0; d0 < DIM; d0 += 4) {
    float4 xv = *(const float4*)(xp + d0);
    const float* xs = (const float*)&xv;
#pragma unroll
    for (int j = 0; j < 4; ++j) {
      float xf = xs[j];
#pragma unroll
      for (int e = 0; e < NEXP; ++e) acc[e] += xf * wr[(d0 + j) * NEXP + e];
    }
  }
  float p[NEXP];
#pragma unroll
  for (int e = 0; e < NEXP; ++e)
    p[e] = 1.f / (1.f + __expf(-acc[e] * bias[e]));
  float best = -1.f; int bi = 0;
#pragma unroll
  for (int e = 0; e < NEXP; ++e) if (p[e] > best) { best = p[e]; bi = e; }
  float sec = -1.f; int si = 0;
#pragma unroll
  for (int e = 0; e < NEXP; ++e) if (e != bi && p[e] > sec) { sec = p[e]; si = e; }
  float s = best + sec;
  eidx[t] = bi | (si << 8);
  ((float2*)ew)[t] = make_float2(best / s, sec / s);
}

// ---------------- X fp32 -> bf16 ----------------
__global__ __launch_bounds__(256) void xcvt_kernel(
    const float* __restrict__ X, unsigned short* __restrict__ Xb)
{
  int i = (blockIdx.x * 256 + threadIdx.x) * 8;
  float4 v0 = *(const float4*)&X[i];
  float4 v1 = *(const float4*)&X[i + 4];
  unsigned short o[8];
  o[0] = f2b(v0.x); o[1] = f2b(v0.y); o[2] = f2b(v0.z); o[3] = f2b(v0.w);
  o[4] = f2b(v1.x); o[5] = f2b(v1.y); o[6] = f2b(v1.z); o[7] = f2b(v1.w);
  *(int4*)&Xb[i] = *(const int4*)o;
}

// ---------------- build4: 256-padded slot lists + map256 (gateup) + routed map128 (down) ----------------
// meta[0]=TOKENS, meta[1+e]=cnt_e ; meta[8]=0, meta[9+e]=TOKENS+ofs256_e
// meta[16]=nblk256 (incl dense), meta[17]=nblk128 routed-only
// meta[32+i]  = map256: eslot | (mb<<4)   (eslot 0=dense, 1..7 routed; mb in 256-row units)
// meta[160+i] = map128r: eslot | (mb<<4)  (routed only; mb in 128-row units)
__global__ __launch_bounds__(256) void build4_kernel(
    const int* __restrict__ eidx, const float* __restrict__ ew,
    int* __restrict__ tok, float* __restrict__ wgt, int* __restrict__ meta)
{
  __shared__ int cnt[NEXP], fill[NEXP], ofs[NEXP];
  const int tid = threadIdx.x;
  const int lane = tid & 63, wid = tid >> 6;
  if (tid < NEXP) { cnt[tid] = 0; fill[tid] = 0; }
  for (int i = tid; i < TOKENS; i += 256) { tok[i] = i; wgt[i] = 1.f; }
  __syncthreads();
  const unsigned long long lmask = (1ull << lane) - 1ull;
  for (int base = wid * 64; base < TOKENS; base += 256) {
    int t = base + lane;
    int p = eidx[t];
    int e0 = p & 0xff, e1 = (p >> 8) & 0xff;
#pragma unroll
    for (int e = 0; e < NEXP; ++e) {
      unsigned long long m0 = __ballot(e0 == e);
      unsigned long long m1 = __ballot(e1 == e);
      if (lane == 0) {
        int tot = __popcll(m0) + __popcll(m1);
        if (tot) atomicAdd(&cnt[e], tot);
      }
    }
  }
  __syncthreads();
  if (tid == 0) {
    int o = 0, nb = 0, nb2 = 0;
    meta[0] = TOKENS; meta[8] = 0;
    for (int i = 0; i < TOKENS / 256; ++i) meta[32 + nb++] = 0 | (i << 4);
    for (int e = 0; e < NEXP; ++e) {
      ofs[e] = o;
      meta[1 + e] = cnt[e];
      meta[9 + e] = TOKENS + o;
      int b = (cnt[e] + 255) >> 8;
      for (int i = 0; i < b; ++i)     meta[32 + nb++]   = (e + 1) | (i << 4);
      for (int i = 0; i < 2 * b; ++i) meta[160 + nb2++] = (e + 1) | (i << 4);
      o += b << 8;
    }
    meta[16] = nb; meta[17] = nb2;
  }
  __syncthreads();
  for (int base = wid * 64; base < TOKENS; base += 256) {
    int t = base + lane;
    int p = eidx[t];
    int e0 = p & 0xff, e1 = (p >> 8) & 0xff;
    float2 w = ((const float2*)ew)[t];
#pragma unroll
    for (int e = 0; e < NEXP; ++e) {
      unsigned long long m0 = __ballot(e0 == e);
      unsigned long long m1 = __ballot(e1 == e);
      int tot = __popcll(m0) + __popcll(m1);
      int wb = 0;
      if (lane == 0 && tot) wb = atomicAdd(&fill[e], tot);
      wb = __shfl(wb, 0);
      if (e0 == e) {
        int sl = TOKENS + ofs[e] + wb + __popcll(m0 & lmask);
        tok[sl] = t; wgt[sl] = w.x;
      }
      if (e1 == e) {
        int sl = TOKENS + ofs[e] + wb + __popcll(m0) + __popcll(m1 & lmask);
        tok[sl] = t; wgt[sl] = w.y;
      }
    }
  }
}

// ---------------- transpose + convert, all experts ----------------
__global__ __launch_bounds__(256) void transpose_all_kernel(
    const float* __restrict__ sg, const float* __restrict__ su, const float* __restrict__ sd,
    const float* __restrict__ rg, const float* __restrict__ ru, const float* __restrict__ rd,
    unsigned short* __restrict__ WguA, unsigned short* __restrict__ WdA)
{
  int b = blockIdx.x;
  int e = b / 2112, r = b % 2112;
  int m = r / 704, q2 = r % 704;
  const float* src; unsigned short* dst; int K, N, nb, kb;
  if (m == 0) {
    src = e ? rg + (size_t)(e - 1) * DIM * HID : sg;
    dst = WguA + (size_t)e * (2 * (size_t)HID * DIM);
    K = DIM; N = HID; nb = q2 % 44; kb = q2 / 44;
  } else if (m == 1) {
    src = e ? ru + (size_t)(e - 1) * DIM * HID : su;
    dst = WguA + (size_t)e * (2 * (size_t)HID * DIM) + (size_t)HID * DIM;
    K = DIM; N = HID; nb = q2 % 44; kb = q2 / 44;
  } else {
    src = e ? rd + (size_t)(e - 1) * HID * DIM : sd;
    dst = WdA + (size_t)e * ((size_t)HID * DIM);
    K = HID; N = DIM; nb = q2 % 16; kb = q2 / 16;
  }
  __shared__ unsigned short t[64][72];
  const int n0 = nb * 64, k0 = kb * 64;
  const int tid = threadIdx.x;
  const int kl = tid >> 4, nl = (tid & 15) * 4;
#pragma unroll
  for (int i = 0; i < 4; ++i) {
    int k = kl + i * 16;
    float4 v = *(const float4*)&src[(size_t)(k0 + k) * N + n0 + nl];
    t[nl + 0][k] = f2b(v.x); t[nl + 1][k] = f2b(v.y);
    t[nl + 2][k] = f2b(v.z); t[nl + 3][k] = f2b(v.w);
  }
  __syncthreads();
  const int nl2 = tid >> 3, kc = (tid & 7) * 8;
#pragma unroll
  for (int i = 0; i < 2; ++i) {
    int n = nl2 + i * 32;
    *(int4*)&dst[(size_t)(n0 + n) * K + k0 + kc] = *(const int4*)&t[n][kc];
  }
}

// ======== gateup_all256: BM=256 (verified addressing), proven 2-barrier loop, NT H-stores ========
__global__ __launch_bounds__(512, 2) void gateup_all256_kernel(
    const unsigned short* __restrict__ Xb,
    const unsigned short* __restrict__ WguA,
    const int* __restrict__ tok, const float* __restrict__ wgt,
    const int* __restrict__ meta,
    unsigned short* __restrict__ H)
{
  const int yb = blockIdx.y;
  if (yb >= meta[16]) return;
  const int ent = meta[32 + yb];
  const int e = ent & 15, mb = ent >> 4;
  const int cnt = meta[e];
  const int pofs = meta[8 + e];
  const int m0 = mb * 256;
  const unsigned short* Wg = WguA + (size_t)e * (2 * (size_t)HID * DIM);
  const unsigned short* Wu = Wg + (size_t)HID * DIM;

  __shared__ __align__(16) unsigned short As[256 * 64];   // 32 KB
  __shared__ __align__(16) unsigned short Bgs[64 * 64];   //  8 KB
  __shared__ __align__(16) unsigned short Bus[64 * 64];   //  8 KB
  __shared__ float wl[256];

  const int tid = threadIdx.x;
  const int lane = tid & 63;
  const int w = tid >> 6;
  const int wmi = w & 3;        // M strip (64 rows)
  const int wni = w >> 2;       // N strip (32 cols)
  const int c = lane & 15;
  const int q = lane >> 4;
  const int cx = c & 7;

  const int srow = tid >> 3;                       // 0..63
  const int swz = ((tid & 7) ^ (srow & 7)) * 8;    // pre-swizzled source granule

  const unsigned short* aptr[4];
#pragma unroll
  for (int i = 0; i < 4; ++i) {
    int s = m0 + i * 64 + srow;
    int t = (s < cnt) ? tok[pofs + s] : 0;
    aptr[i] = Xb + (size_t)t * DIM + swz;
  }
  const int n0 = blockIdx.x * 64;
  const unsigned short* gptr = Wg + (size_t)(n0 + srow) * DIM + swz;
  const unsigned short* uptr = Wu + (size_t)(n0 + srow) * DIM + swz;

  if (tid < 256) wl[tid] = (m0 + tid < cnt) ? wgt[pofs + m0 + tid] : 0.f;

  f32x4 accg[4][2], accu[4][2];
#pragma unroll
  for (int mi = 0; mi < 4; ++mi)
#pragma unroll
    for (int ni = 0; ni < 2; ++ni) {
      accg[mi][ni] = {0.f, 0.f, 0.f, 0.f};
      accu[mi][ni] = {0.f, 0.f, 0.f, 0.f};
    }

  for (int k0 = 0; k0 < DIM; k0 += 64) {
    __syncthreads();
#pragma unroll
    for (int i = 0; i < 4; ++i) gload16(aptr[i] + k0, &As[i * 4096 + tid * 8]);
    gload16(gptr + k0, &Bgs[tid * 8]);
    gload16(uptr + k0, &Bus[tid * 8]);
    __syncthreads();
#pragma unroll
    for (int h = 0; h < 2; ++h) {
      const int go = ((h * 4 + q) ^ cx) * 8;
      bf16x8 a[4], bg[2], bu[2];
#pragma unroll
      for (int mi = 0; mi < 4; ++mi)
        a[mi] = *(const bf16x8*)&As[(wmi * 64 + mi * 16 + c) * 64 + go];
#pragma unroll
      for (int ni = 0; ni < 2; ++ni) {
        bg[ni] = *(const bf16x8*)&Bgs[(wni * 32 + ni * 16 + c) * 64 + go];
        bu[ni] = *(const bf16x8*)&Bus[(wni * 32 + ni * 16 + c) * 64 + go];
      }
#pragma unroll
      for (int mi = 0; mi < 4; ++mi)
#pragma unroll
        for (int ni = 0; ni < 2; ++ni) {
          accg[mi][ni] = __builtin_amdgcn_mfma_f32_16x16x32_bf16(a[mi], bg[ni], accg[mi][ni], 0, 0, 0);
          accu[mi][ni] = __builtin_amdgcn_mfma_f32_16x16x32_bf16(a[mi], bu[ni], accu[mi][ni], 0, 0, 0);
        }
    }
  }
#pragma unroll
  for (int mi = 0; mi < 4; ++mi)
#pragma unroll
    for (int ni = 0; ni < 2; ++ni)
#pragma unroll
      for (int r = 0; r < 4; ++r) {
        int row = wmi * 64 + mi * 16 + q * 4 + r;
        int col = wni * 32 + ni * 16 + c;
        float g = accg[mi][ni][r];
        float u = accu[mi][ni][r];
        float h = (g / (1.f + __expf(-g))) * u * wl[row];
        unsigned short hv = f2b(h);
        __builtin_nontemporal_store(hv, &H[(size_t)(pofs + m0 + row) * HID + n0 + col]);
      }
}

// ---------------- dense down (tokens 0..8192, initializes out) ----------------
__global__ __launch_bounds__(256, 2) void down_dense_kernel(
    const unsigned short* __restrict__ Hm,
    const unsigned short* __restrict__ WdT,
    float* __restrict__ out)
{
  __shared__ __align__(16) unsigned short As[128 * 64];
  __shared__ __align__(16) unsigned short Bs[128 * 64];
  const int m0 = blockIdx.y * 128;
  const int n0 = blockIdx.x * 128;
  const int tid = threadIdx.x;
  const int lane = tid & 63;
  const int w4 = tid >> 6;
  const int wm = (w4 & 1) * 64;
  const int wn = (w4 >> 1) * 64;
  const int c = lane & 15;
  const int q = lane >> 4;
  const int cx = c & 7;
  const int r8 = lane >> 3;
  const int swz = ((lane & 7) ^ r8) * 8;
  const int wrow = w4 * 8 + r8;
  const unsigned short* aptr[4];
  const unsigned short* bptr[4];
#pragma unroll
  for (int i = 0; i < 4; ++i) {
    aptr[i] = Hm + (size_t)(m0 + i * 32 + wrow) * HID + swz;
    bptr[i] = WdT + (size_t)(n0 + i * 32 + wrow) * HID + swz;
  }
  f32x4 acc[4][4];
#pragma unroll
  for (int mi = 0; mi < 4; ++mi)
#pragma unroll
    for (int ni = 0; ni < 4; ++ni) acc[mi][ni] = {0.f, 0.f, 0.f, 0.f};
  for (int k0 = 0; k0 < HID; k0 += 64) {
    __syncthreads();
#pragma unroll
    for (int i = 0; i < 4; ++i) {
      gload16(aptr[i] + k0, &As[i * 2048 + tid * 8]);
      gload16(bptr[i] + k0, &Bs[i * 2048 + tid * 8]);
    }
    __syncthreads();
#pragma unroll
    for (int h = 0; h < 2; ++h) {
      const int go = ((h * 4 + q) ^ cx) * 8;
      bf16x8 a[4], bb[4];
#pragma unroll
      for (int mi = 0; mi < 4; ++mi)
        a[mi] = *(const bf16x8*)&As[(wm + mi * 16 + c) * 64 + go];
#pragma unroll
      for (int ni = 0; ni < 4; ++ni)
        bb[ni] = *(const bf16x8*)&Bs[(wn + ni * 16 + c) * 64 + go];
#pragma unroll
      for (int mi = 0; mi < 4; ++mi)
#pragma unroll
        for (int ni = 0; ni < 4; ++ni)
          acc[mi][ni] = __builtin_amdgcn_mfma_f32_16x16x32_bf16(a[mi], bb[ni], acc[mi][ni], 0, 0, 0);
    }
  }
#pragma unroll
  for (int mi = 0; mi < 4; ++mi)
#pragma unroll
    for (int r = 0; r < 4; ++r) {
      int trow = m0 + wm + mi * 16 + q * 4 + r;
#pragma unroll
      for (int ni = 0; ni < 4; ++ni) {
        int col = n0 + wn + ni * 16 + c;
        out[(size_t)trow * DIM + col] = acc[mi][ni][r];
      }
    }
}

// ---------------- routed down (tier-1): 128-map over 256-padded slots, split-K=2, atomics ----------------
__global__ __launch_bounds__(256, 2) void down_routed_kernel(
    const unsigned short* __restrict__ Hm,
    const unsigned short* __restrict__ WdA,
    const int* __restrict__ tok, const int* __restrict__ meta,
    float* __restrict__ out)
{
  const int yb = blockIdx.y;
  if (yb >= meta[17]) return;
  const int ent = meta[160 + yb];
  const int e = ent & 15, mb = ent >> 4;     // e = 1..7 (routed slot), mb in 128-row units
  const int cnt = meta[e];
  const int pofs = meta[8 + e];
  const unsigned short* WdT = WdA + (size_t)e * ((size_t)HID * DIM);
  const int kbase = blockIdx.z * (HID / 2);

  __shared__ __align__(16) unsigned short As[128 * 64];
  __shared__ __align__(16) unsigned short Bs[128 * 64];
  __shared__ int tl[128];
  const int n0 = blockIdx.x * 128;
  const int tid = threadIdx.x;
  const int lane = tid & 63;
  const int w4 = tid >> 6;
  const int wm = (w4 & 1) * 64;
  const int wn = (w4 >> 1) * 64;
  const int c = lane & 15;
  const int q = lane >> 4;
  const int cx = c & 7;
  if (tid < 128)
    tl[tid] = (mb * 128 + tid < cnt) ? tok[pofs + mb * 128 + tid] : 0;
  const int r8 = lane >> 3;
  const int swz = ((lane & 7) ^ r8) * 8;
  const int wrow = w4 * 8 + r8;
  const unsigned short* aptr[4];
  const unsigned short* bptr[4];
#pragma unroll
  for (int i = 0; i < 4; ++i) {
    aptr[i] = Hm + (size_t)(pofs + mb * 128 + i * 32 + wrow) * HID + kbase + swz;
    bptr[i] = WdT + (size_t)(n0 + i * 32 + wrow) * HID + kbase + swz;
  }
  f32x4 acc[4][4];
#pragma unroll
  for (int mi = 0; mi < 4; ++mi)
#pragma unroll
    for (int ni = 0; ni < 4; ++ni) acc[mi][ni] = {0.f, 0.f, 0.f, 0.f};
  for (int k0 = 0; k0 < HID / 2; k0 += 64) {
    __syncthreads();
#pragma unroll
    for (int i = 0; i < 4; ++i) {
      gload16(aptr[i] + k0, &As[i * 2048 + tid * 8]);
      gload16(bptr[i] + k0, &Bs[i * 2048 + tid * 8]);
    }
    __syncthreads();
#pragma unroll
    for (int h = 0; h < 2; ++h) {
      const int go = ((h * 4 + q) ^ cx) * 8;
      bf16x8 a[4], bb[4];
#pragma unroll
      for (int mi = 0; mi < 4; ++mi)
        a[mi] = *(const bf16x8*)&As[(wm + mi * 16 + c) * 64 + go];
#pragma unroll
      for (int ni = 0; ni < 4; ++ni)
        bb[ni] = *(const bf16x8*)&Bs[(wn + ni * 16 + c) * 64 + go];
#pragma unroll
      for (int mi = 0; mi < 4; ++mi)
#pragma unroll
        for (int ni = 0; ni < 4; ++ni)
          acc[mi][ni] = __builtin_amdgcn_mfma_f32_16x16x32_bf16(a[mi], bb[ni], acc[mi][ni], 0, 0, 0);
    }
  }
#pragma unroll
  for (int mi = 0; mi < 4; ++mi)
#pragma unroll
    for (int r = 0; r < 4; ++r) {
      int lr = wm + mi * 16 + q * 4 + r;
      if (mb * 128 + lr < cnt) {
        int t = tl[lr];
#pragma unroll
        for (int ni = 0; ni < 4; ++ni) {
          int col = n0 + wn + ni * 16 + c;
          atomicAdd(&out[(size_t)t * DIM + col], acc[mi][ni][r]);
        }
      }
    }
}

// ================= R2 fallback kernels (proven path, used if ws too small) =================
__global__ __launch_bounds__(256) void build_kernel(
    const int* __restrict__ eidx, const float* __restrict__ ew,
    int* __restrict__ tok, float* __restrict__ wgt, int* __restrict__ meta,
    int padmode)
{
  __shared__ int cnt[NEXP], fill[NEXP], ofs[NEXP];
  if (threadIdx.x < NEXP) { cnt[threadIdx.x] = 0; fill[threadIdx.x] = 0; }
  __syncthreads();
  for (int t = threadIdx.x; t < TOKENS; t += 256) {
    int p = eidx[t];
    atomicAdd(&cnt[p & 0xff], 1);
    atomicAdd(&cnt[(p >> 8) & 0xff], 1);
  }
  __syncthreads();
  if (threadIdx.x == 0) {
    int o = 0, nb = 0;
    for (int e = 0; e < NEXP; ++e) {
      ofs[e] = o;
      meta[e] = cnt[e];
      meta[8 + e] = o;
      if (padmode) {
        int b = (cnt[e] + 127) >> 7;
        for (int i = 0; i < b; ++i) meta[16 + nb++] = e | (i << 3);
        o += b << 7;
      } else {
        o += cnt[e];
      }
    }
    meta[15] = nb;
  }
  __syncthreads();
  for (int t = threadIdx.x; t < TOKENS; t += 256) {
    int p = eidx[t];
    int e0 = p & 0xff, e1 = (p >> 8) & 0xff;
    float2 w = ((const float2*)ew)[t];
    int p0 = ofs[e0] + atomicAdd(&fill[e0], 1);
    tok[p0] = t; wgt[p0] = w.x;
    int p1 = ofs[e1] + atomicAdd(&fill[e1], 1);
    tok[p1] = t; wgt[p1] = w.y;
  }
}

__global__ __launch_bounds__(256, 2) void gateup_kernel(
    const unsigned short* __restrict__ Xb,
    const unsigned short* __restrict__ Wgu,
    unsigned short* __restrict__ H)
{
  __shared__ __align__(16) unsigned short As[128 * 64];
  __shared__ __align__(16) unsigned short Bgs[64 * 64];
  __shared__ __align__(16) unsigned short Bus[64 * 64];
  const int m0 = blockIdx.y * 128;
  const int n0 = blockIdx.x * 64;
  const int tid = threadIdx.x;
  const int lane = tid & 63;
  const int w = tid >> 6;
  const int wm = (w & 1) * 64;
  const int wn = (w >> 1) * 32;
  const int c = lane & 15;
  const int q = lane >> 4;
  const int cx = c & 7;
  const unsigned short* Wg = Wgu;
  const unsigned short* Wu = Wgu + (size_t)HID * DIM;
  const int r8 = lane >> 3;
  const int swz = ((lane & 7) ^ r8) * 8;
  const int wrow = w * 8 + r8;
  const unsigned short* aptr[4];
#pragma unroll
  for (int i = 0; i < 4; ++i)
    aptr[i] = Xb + (size_t)(m0 + i * 32 + wrow) * DIM + swz;
  const unsigned short* gptr[2];
  const unsigned short* uptr[2];
#pragma unroll
  for (int i = 0; i < 2; ++i) {
    gptr[i] = Wg + (size_t)(n0 + i * 32 + wrow) * DIM + swz;
    uptr[i] = Wu + (size_t)(n0 + i * 32 + wrow) * DIM + swz;
  }
  f32x4 accg[4][2], accu[4][2];
#pragma unroll
  for (int mi = 0; mi < 4; ++mi)
#pragma unroll
    for (int ni = 0; ni < 2; ++ni) {
      accg[mi][ni] = {0.f, 0.f, 0.f, 0.f};
      accu[mi][ni] = {0.f, 0.f, 0.f, 0.f};
    }
  for (int k0 = 0; k0 < DIM; k0 += 64) {
    __syncthreads();
#pragma unroll
    for (int i = 0; i < 4; ++i) gload16(aptr[i] + k0, &As[i * 2048 + tid * 8]);
#pragma unroll
    for (int i = 0; i < 2; ++i) {
      gload16(gptr[i] + k0, &Bgs[i * 2048 + tid * 8]);
      gload16(uptr[i] + k0, &Bus[i * 2048 + tid * 8]);
    }
    __syncthreads();
#pragma unroll
    for (int h = 0; h < 2; ++h) {
      const int go = ((h * 4 + q) ^ cx) * 8;
      bf16x8 a[4], bg[2], bu[2];
#pragma unroll
      for (int mi = 0; mi < 4; ++mi)
        a[mi] = *(const bf16x8*)&As[(wm + mi * 16 + c) * 64 + go];
#pragma unroll
      for (int ni = 0; ni < 2; ++ni) {
        bg[ni] = *(const bf16x8*)&Bgs[(wn + ni * 16 + c) * 64 + go];
        bu[ni] = *(const bf16x8*)&Bus[(wn + ni * 16 + c) * 64 + go];
      }
#pragma unroll
      for (int mi = 0; mi < 4; ++mi)
#pragma unroll
        for (int ni = 0; ni < 2; ++ni) {
          accg[mi][ni] = __builtin_amdgcn_mfma_f32_16x16x32_bf16(a[mi], bg[ni], accg[mi][ni], 0, 0, 0);
          accu[mi][ni] = __builtin_amdgcn_mfma_f32_16x16x32_bf16(a[mi], bu[ni], accu[mi][ni], 0, 0, 0);
        }
    }
  }
#pragma unroll
  for (int mi = 0; mi < 4; ++mi)
#pragma unroll
    for (int ni = 0; ni < 2; ++ni)
#pragma unroll
      for (int r = 0; r < 4; ++r) {
        int row = wm + mi * 16 + q * 4 + r;
        int col = wn + ni * 16 + c;
        float g = accg[mi][ni][r];
        float u = accu[mi][ni][r];
        float h = (g / (1.f + __expf(-g))) * u;
        H[(size_t)(m0 + row) * HID + n0 + col] = f2b(h);
      }
}

__global__ __launch_bounds__(256, 2) void gateup_sparse_all_kernel(
    const unsigned short* __restrict__ Xb,
    const unsigned short* __restrict__ WguR,
    const int* __restrict__ tok, const float* __restrict__ wgt,
    const int* __restrict__ meta,
    unsigned short* __restrict__ H)
{
  const int yb = blockIdx.y;
  if (yb >= meta[15]) return;
  const int bm = meta[16 + yb];
  const int e = bm & 7, mb = bm >> 3;
  const int cnt = meta[e];
  const int pofs = meta[8 + e];
  const unsigned short* Wgu = WguR + (size_t)e * (2 * (size_t)HID * DIM);
  __shared__ __align__(16) unsigned short As[128 * 64];
  __shared__ __align__(16) unsigned short Bgs[64 * 64];
  __shared__ __align__(16) unsigned short Bus[64 * 64];
  __shared__ float wl[128];
  const int n0 = blockIdx.x * 64;
  const int tid = threadIdx.x;
  const int lane = tid & 63;
  const int w = tid >> 6;
  const int wm = (w & 1) * 64;
  const int wn = (w >> 1) * 32;
  const int c = lane & 15;
  const int q = lane >> 4;
  const int cx = c & 7;
  if (tid < 128)
    wl[tid] = (mb * 128 + tid < cnt) ? wgt[pofs + mb * 128 + tid] : 0.f;
  const unsigned short* Wg = Wgu;
  const unsigned short* Wu = Wgu + (size_t)HID * DIM;
  const int r8 = lane >> 3;
  const int swz = ((lane & 7) ^ r8) * 8;
  const int wrow = w * 8 + r8;
  const unsigned short* aptr[4];
#pragma unroll
  for (int i = 0; i < 4; ++i) {
    int s = mb * 128 + i * 32 + wrow;
    int t = (s < cnt) ? tok[pofs + s] : 0;
    aptr[i] = Xb + (size_t)t * DIM + swz;
  }
  const unsigned short* gptr[2];
  const unsigned short* uptr[2];
#pragma unroll
  for (int i = 0; i < 2; ++i) {
    gptr[i] = Wg + (size_t)(n0 + i * 32 + wrow) * DIM + swz;
    uptr[i] = Wu + (size_t)(n0 + i * 32 + wrow) * DIM + swz;
  }
  f32x4 accg[4][2], accu[4][2];
#pragma unroll
  for (int mi = 0; mi < 4; ++mi)
#pragma unroll
    for (int ni = 0; ni < 2; ++ni) {
      accg[mi][ni] = {0.f, 0.f, 0.f, 0.f};
      accu[mi][ni] = {0.f, 0.f, 0.f, 0.f};
    }
  for (int k0 = 0; k0 < DIM; k0 += 64) {
    __syncthreads();
#pragma unroll
    for (int i = 0; i < 4; ++i) gload16(aptr[i] + k0, &As[i * 2048 + tid * 8]);
#pragma unroll
    for (int i = 0; i < 2; ++i) {
      gload16(gptr[i] + k0, &Bgs[i * 2048 + tid * 8]);
      gload16(uptr[i] + k0, &Bus[i * 2048 + tid * 8]);
    }
    __syncthreads();
#pragma unroll
    for (int h = 0; h < 2; ++h) {
      const int go = ((h * 4 + q) ^ cx) * 8;
      bf16x8 a[4], bg[2], bu[2];
#pragma unroll
      for (int mi = 0; mi < 4; ++mi)
        a[mi] = *(const bf16x8*)&As[(wm + mi * 16 + c) * 64 + go];
#pragma unroll
      for (int ni = 0; ni < 2; ++ni) {
        bg[ni] = *(const bf16x8*)&Bgs[(wn + ni * 16 + c) * 64 + go];
        bu[ni] = *(const bf16x8*)&Bus[(wn + ni * 16 + c) * 64 + go];
      }
#pragma unroll
      for (int mi = 0; mi < 4; ++mi)
#pragma unroll
        for (int ni = 0; ni < 2; ++ni) {
          accg[mi][ni] = __builtin_amdgcn_mfma_f32_16x16x32_bf16(a[mi], bg[ni], accg[mi][ni], 0, 0, 0);
          accu[mi][ni] = __builtin_amdgcn_mfma_f32_16x16x32_bf16(a[mi], bu[ni], accu[mi][ni], 0, 0, 0);
        }
    }
  }
#pragma unroll
  for (int mi = 0; mi < 4; ++mi)
#pragma unroll
    for (int ni = 0; ni < 2; ++ni)
#pragma unroll
      for (int r = 0; r < 4; ++r) {
        int row = wm + mi * 16 + q * 4 + r;
        int col = wn + ni * 16 + c;
        float g = accg[mi][ni][r];
        float u = accu[mi][ni][r];
        float h = (g / (1.f + __expf(-g))) * u * wl[row];
        H[(size_t)(pofs + mb * 128 + row) * HID + n0 + col] = f2b(h);
      }
}

__global__ __launch_bounds__(256, 2) void down_sparse_all_kernel(
    const unsigned short* __restrict__ Hm,
    const unsigned short* __restrict__ WdR,
    const int* __restrict__ tok, const int* __restrict__ meta,
    float* __restrict__ out)
{
  const int yb = blockIdx.y;
  if (yb >= meta[15]) return;
  const int bm = meta[16 + yb];
  const int e = bm & 7, mb = bm >> 3;
  const int cnt = meta[e];
  const int pofs = meta[8 + e];
  const unsigned short* WdT = WdR + (size_t)e * ((size_t)HID * DIM);
  const int kbase = blockIdx.z * (HID / 2);
  __shared__ __align__(16) unsigned short As[128 * 64];
  __shared__ __align__(16) unsigned short Bs[128 * 64];
  __shared__ int tl[128];
  const int n0 = blockIdx.x * 128;
  const int tid = threadIdx.x;
  const int lane = tid & 63;
  const int w4 = tid >> 6;
  const int wm = (w4 & 1) * 64;
  const int wn = (w4 >> 1) * 64;
  const int c = lane & 15;
  const int q = lane >> 4;
  const int cx = c & 7;
  if (tid < 128)
    tl[tid] = (mb * 128 + tid < cnt) ? tok[pofs + mb * 128 + tid] : 0;
  const int r8 = lane >> 3;
  const int swz = ((lane & 7) ^ r8) * 8;
  const int wrow = w4 * 8 + r8;
  const unsigned short* aptr[4];
  const unsigned short* bptr[4];
#pragma unroll
  for (int i = 0; i < 4; ++i) {
    aptr[i] = Hm + (size_t)(pofs + mb * 128 + i * 32 + wrow) * HID + kbase + swz;
    bptr[i] = WdT + (size_t)(n0 + i * 32 + wrow) * HID + kbase + swz;
  }
  f32x4 acc[4][4];
#pragma unroll
  for (int mi = 0; mi < 4; ++mi)
#pragma unroll
    for (int ni = 0; ni < 4; ++ni) acc[mi][ni] = {0.f, 0.f, 0.f, 0.f};
  for (int k0 = 0; k0 < HID / 2; k0 += 64) {
    __syncthreads();
#pragma unroll
    for (int i = 0; i < 4; ++i) {
      gload16(aptr[i] + k0, &As[i * 2048 + tid * 8]);
      gload16(bptr[i] + k0, &Bs[i * 2048 + tid * 8]);
    }
    __syncthreads();
#pragma unroll
    for (int h = 0; h < 2; ++h) {
      const int go = ((h * 4 + q) ^ cx) * 8;
      bf16x8 a[4], bb[4];
#pragma unroll
      for (int mi = 0; mi < 4; ++mi)
        a[mi] = *(const bf16x8*)&As[(wm + mi * 16 + c) * 64 + go];
#pragma unroll
      for (int ni = 0; ni < 4; ++ni)
        bb[ni] = *(const bf16x8*)&Bs[(wn + ni * 16 + c) * 64 + go];
#pragma unroll
      for (int mi = 0; mi < 4; ++mi)
#pragma unroll
        for (int ni = 0; ni < 4; ++ni)
          acc[mi][ni] = __builtin_amdgcn_mfma_f32_16x16x32_bf16(a[mi], bb[ni], acc[mi][ni], 0, 0, 0);
    }
  }
#pragma unroll
  for (int mi = 0; mi < 4; ++mi)
#pragma unroll
    for (int r = 0; r < 4; ++r) {
      int lr = wm + mi * 16 + q * 4 + r;
      if (mb * 128 + lr < cnt) {
        int t = tl[lr];
#pragma unroll
        for (int ni = 0; ni < 4; ++ni) {
          int col = n0 + wn + ni * 16 + c;
          atomicAdd(&out[(size_t)t * DIM + col], acc[mi][ni][r]);
        }
      }
    }
}

extern "C" void kernel_launch(void* const* d_in, const int* in_sizes, int n_in,
                              void* d_out, int out_size, void* d_ws, size_t ws_size,
                              hipStream_t stream) {
  (void)in_sizes; (void)n_in; (void)out_size;
  const float* x   = (const float*)d_in[0];
  const float* sg  = (const float*)d_in[1];
  const float* su  = (const float*)d_in[2];
  const float* sd  = (const float*)d_in[3];
  const float* rg  = (const float*)d_in[4];
  const float* ru  = (const float*)d_in[5];
  const float* rd  = (const float*)d_in[6];
  const float* wrr = (const float*)d_in[7];
  const float* rb  = (const float*)d_in[8];
  float* out = (float*)d_out;

  char* ws = (char*)d_ws;
  dim3 blk(256);

  if (ws_size >= MW3_NEED) {
    // -------- tier-1: BM=256 NT-store gateup + R2-proven atomic down --------
    unsigned short* Xb   = (unsigned short*)(ws + MW3_XB);
    unsigned short* WguA = (unsigned short*)(ws + MW3_WGU);
    unsigned short* WdA  = (unsigned short*)(ws + MW3_WD);
    unsigned short* H    = (unsigned short*)(ws + MW3_H);
    int*   tok           = (int*)(ws + MW3_TOK);
    float* wgt           = (float*)(ws + MW3_WGT);
    int*   meta          = (int*)(ws + MW3_META);
    int*   eidx = (int*)H;                       // parked in H, consumed by build
    float* ew   = (float*)((char*)H + 32768);

    router_kernel<<<dim3(TOKENS / 256), blk, 0, stream>>>(x, wrr, rb, eidx, ew);
    xcvt_kernel<<<dim3(TOKENS * DIM / (8 * 256)), blk, 0, stream>>>(x, Xb);
    build4_kernel<<<dim3(1), blk, 0, stream>>>(eidx, ew, tok, wgt, meta);
    transpose_all_kernel<<<dim3(8 * 2112), blk, 0, stream>>>(sg, su, sd, rg, ru, rd, WguA, WdA);
    gateup_all256_kernel<<<dim3(HID / 64, 104), dim3(512), 0, stream>>>(Xb, WguA, tok, wgt, meta, H);
    down_dense_kernel<<<dim3(DIM / 128, TOKENS / 128), blk, 0, stream>>>(H, WdA, out);
    down_routed_kernel<<<dim3(DIM / 128, 144, 2), blk, 0, stream>>>(H, WdA, tok, meta, out);
  } else {
    // -------- fallback: proven R2 merged schedule --------
    unsigned short* Xb   = (unsigned short*)(ws + MW_XB);
    unsigned short* H    = (unsigned short*)(ws + MW_H);
    unsigned short* WguA = (unsigned short*)(ws + MW_WGU);
    unsigned short* WdA  = (unsigned short*)(ws + MW_WD);
    int*   tok           = (int*)(ws + MW_TOK);
    float* wgt           = (float*)(ws + MW_WGT);
    int*   meta          = (int*)(ws + MW_META);
    int*   eidx = (int*)H;
    float* ew   = (float*)((char*)H + 32768);

    router_kernel<<<dim3(TOKENS / 256), blk, 0, stream>>>(x, wrr, rb, eidx, ew);
    xcvt_kernel<<<dim3(TOKENS * DIM / (8 * 256)), blk, 0, stream>>>(x, Xb);
    build_kernel<<<dim3(1), blk, 0, stream>>>(eidx, ew, tok, wgt, meta, 1);
    transpose_all_kernel<<<dim3(8 * 2112), blk, 0, stream>>>(sg, su, sd, rg, ru, rd, WguA, WdA);
    gateup_kernel<<<dim3(HID / 64, TOKENS / 128), blk, 0, stream>>>(Xb, WguA, H);
    down_dense_kernel<<<dim3(DIM / 128, TOKENS / 128), blk, 0, stream>>>(H, WdA, out);
    const unsigned short* WguRt = WguA + 2 * (size_t)HID * DIM;
    const unsigned short* WdRt  = WdA + (size_t)HID * DIM;
    gateup_sparse_all_kernel<<<dim3(HID / 64, 135), blk, 0, stream>>>(Xb, WguRt, tok, wgt, meta, H);
    down_sparse_all_kernel<<<dim3(DIM / 128, 135, 2), blk, 0, stream>>>(H, WdRt, tok, meta, out);
  }
}

// Round 9
// 925.341 us; speedup vs baseline: 1.1198x; 1.0797x over previous
//
#include <hip/hip_runtime.h>
#include <hip/hip_bf16.h>

#define DIM 1024
#define HID 2816
#define NEXP 7
#define TOKENS 8192

// ---- workspace layout (bytes) — R2-proven ----
#define MW_XB    0ull
#define MW_H     16777216ull
#define MW_WGU   114098176ull
#define MW_WD    206372864ull
#define MW_TOK   252510208ull
#define MW_WGT   252579328ull
#define MW_META  252648448ull
#define MW_NEED  252650496ull

typedef __bf16 bf16x8 __attribute__((ext_vector_type(8)));
typedef float f32x4 __attribute__((ext_vector_type(4)));

static __device__ __forceinline__ unsigned short f2b(float f) {
  union { float f; unsigned int i; } c; c.f = f;
  unsigned int i = c.i;
  unsigned int r = (i + 0x7fffu + ((i >> 16) & 1u)) >> 16;
  return (unsigned short)r;
}

// async global->LDS, 16 bytes per lane. Global addr is per-lane; LDS dest = wave base + lane*16.
static __device__ __forceinline__ void gload16(const void* g, void* l) {
  __builtin_amdgcn_global_load_lds(
      (const __attribute__((address_space(1))) unsigned int*)g,
      (__attribute__((address_space(3))) unsigned int*)l, 16, 0, 0);
}

// ---------------- fused router + X->bf16: one pass over X ----------------
__global__ __launch_bounds__(256, 2) void router_xcvt_kernel(
    const float* __restrict__ X,
    const float* __restrict__ Wr,
    const float* __restrict__ bias,
    unsigned short* __restrict__ Xb,
    int* __restrict__ eidx,     // packed e0 | e1<<8
    float* __restrict__ ew)     // float2 (w0,w1)
{
  __shared__ float wr[DIM * NEXP];
  for (int i = threadIdx.x; i < DIM * NEXP; i += 256) wr[i] = Wr[i];
  __syncthreads();
  int t = blockIdx.x * 256 + threadIdx.x;
  float acc[NEXP];
#pragma unroll
  for (int e = 0; e < NEXP; ++e) acc[e] = 0.f;
  const float* xp = X + (size_t)t * DIM;
  unsigned short* xbp = Xb + (size_t)t * DIM;
  for (int d0 = 0; d0 < DIM; d0 += 8) {
    float4 v0 = *(const float4*)(xp + d0);
    float4 v1 = *(const float4*)(xp + d0 + 4);
    float xs[8] = {v0.x, v0.y, v0.z, v0.w, v1.x, v1.y, v1.z, v1.w};
    unsigned short o[8];
#pragma unroll
    for (int j = 0; j < 8; ++j) {
      float xf = xs[j];
      o[j] = f2b(xf);
#pragma unroll
      for (int e = 0; e < NEXP; ++e) acc[e] += xf * wr[(d0 + j) * NEXP + e];
    }
    *(int4*)&xbp[d0] = *(const int4*)o;
  }
  float p[NEXP];
#pragma unroll
  for (int e = 0; e < NEXP; ++e)
    p[e] = 1.f / (1.f + __expf(-acc[e] * bias[e]));
  float best = -1.f; int bi = 0;
#pragma unroll
  for (int e = 0; e < NEXP; ++e) if (p[e] > best) { best = p[e]; bi = e; }
  float sec = -1.f; int si = 0;
#pragma unroll
  for (int e = 0; e < NEXP; ++e) if (e != bi && p[e] > sec) { sec = p[e]; si = e; }
  float s = best + sec;
  eidx[t] = bi | (si << 8);
  ((float2*)ew)[t] = make_float2(best / s, sec / s);
}

// ---------------- build per-expert slot lists (128-padded) + block map ----------------
// meta[e]=cnt[e]; meta[8+e]=slot base; meta[15]=nblk; meta[16+i]=blkmap e|(mb<<3)
__global__ __launch_bounds__(256) void build_kernel(
    const int* __restrict__ eidx, const float* __restrict__ ew,
    int* __restrict__ tok, float* __restrict__ wgt, int* __restrict__ meta)
{
  __shared__ int cnt[NEXP], fill[NEXP], ofs[NEXP];
  if (threadIdx.x < NEXP) { cnt[threadIdx.x] = 0; fill[threadIdx.x] = 0; }
  __syncthreads();
  for (int t = threadIdx.x; t < TOKENS; t += 256) {
    int p = eidx[t];
    atomicAdd(&cnt[p & 0xff], 1);
    atomicAdd(&cnt[(p >> 8) & 0xff], 1);
  }
  __syncthreads();
  if (threadIdx.x == 0) {
    int o = 0, nb = 0;
    for (int e = 0; e < NEXP; ++e) {
      ofs[e] = o;
      meta[e] = cnt[e];
      meta[8 + e] = o;
      int b = (cnt[e] + 127) >> 7;
      for (int i = 0; i < b; ++i) meta[16 + nb++] = e | (i << 3);
      o += b << 7;
    }
    meta[15] = nb;
  }
  __syncthreads();
  for (int t = threadIdx.x; t < TOKENS; t += 256) {
    int p = eidx[t];
    int e0 = p & 0xff, e1 = (p >> 8) & 0xff;
    float2 w = ((const float2*)ew)[t];
    int p0 = ofs[e0] + atomicAdd(&fill[e0], 1);
    tok[p0] = t; wgt[p0] = w.x;
    int p1 = ofs[e1] + atomicAdd(&fill[e1], 1);
    tok[p1] = t; wgt[p1] = w.y;
  }
}

// ---------------- transpose + convert, all experts, exact flat grid ----------------
__global__ __launch_bounds__(256) void transpose_all_kernel(
    const float* __restrict__ sg, const float* __restrict__ su, const float* __restrict__ sd,
    const float* __restrict__ rg, const float* __restrict__ ru, const float* __restrict__ rd,
    unsigned short* __restrict__ WguA, unsigned short* __restrict__ WdA)
{
  int b = blockIdx.x;
  int e = b / 2112, r = b % 2112;
  int m = r / 704, q2 = r % 704;
  const float* src; unsigned short* dst; int K, N, nb, kb;
  if (m == 0) {
    src = e ? rg + (size_t)(e - 1) * DIM * HID : sg;
    dst = WguA + (size_t)e * (2 * (size_t)HID * DIM);
    K = DIM; N = HID; nb = q2 % 44; kb = q2 / 44;
  } else if (m == 1) {
    src = e ? ru + (size_t)(e - 1) * DIM * HID : su;
    dst = WguA + (size_t)e * (2 * (size_t)HID * DIM) + (size_t)HID * DIM;
    K = DIM; N = HID; nb = q2 % 44; kb = q2 / 44;
  } else {
    src = e ? rd + (size_t)(e - 1) * HID * DIM : sd;
    dst = WdA + (size_t)e * ((size_t)HID * DIM);
    K = HID; N = DIM; nb = q2 % 16; kb = q2 / 16;
  }
  __shared__ unsigned short t[64][72];
  const int n0 = nb * 64, k0 = kb * 64;
  const int tid = threadIdx.x;
  const int kl = tid >> 4, nl = (tid & 15) * 4;
#pragma unroll
  for (int i = 0; i < 4; ++i) {
    int k = kl + i * 16;
    float4 v = *(const float4*)&src[(size_t)(k0 + k) * N + n0 + nl];
    t[nl + 0][k] = f2b(v.x); t[nl + 1][k] = f2b(v.y);
    t[nl + 2][k] = f2b(v.z); t[nl + 3][k] = f2b(v.w);
  }
  __syncthreads();
  const int nl2 = tid >> 3, kc = (tid & 7) * 8;
#pragma unroll
  for (int i = 0; i < 2; ++i) {
    int n = nl2 + i * 32;
    *(int4*)&dst[(size_t)(n0 + n) * K + k0 + kc] = *(const int4*)&t[n][kc];
  }
}

// ======== BK=64 GEMM kernels with XOR-swizzled LDS (conflict-free ds_read_b128) ========
// LDS tile rows are 128 B (64 bf16) = 8 granules of 16 B. LDS (row, g) holds global
// (row, g ^ (row&7)). Staging pre-swizzles the GLOBAL source; readers XOR with (c&7).

// ---------------- dense fused gate+up (shared expert) ----------------
__global__ __launch_bounds__(256, 2) void gateup_kernel(
    const unsigned short* __restrict__ Xb,
    const unsigned short* __restrict__ Wgu,
    unsigned short* __restrict__ H)
{
  __shared__ __align__(16) unsigned short As[128 * 64];
  __shared__ __align__(16) unsigned short Bgs[64 * 64];
  __shared__ __align__(16) unsigned short Bus[64 * 64];
  const int m0 = blockIdx.y * 128;
  const int n0 = blockIdx.x * 64;
  const int tid = threadIdx.x;
  const int lane = tid & 63;
  const int w = tid >> 6;
  const int wm = (w & 1) * 64;
  const int wn = (w >> 1) * 32;
  const int c = lane & 15;
  const int q = lane >> 4;
  const int cx = c & 7;
  const unsigned short* Wg = Wgu;
  const unsigned short* Wu = Wgu + (size_t)HID * DIM;
  const int r8 = lane >> 3;
  const int swz = ((lane & 7) ^ r8) * 8;
  const int wrow = w * 8 + r8;
  const unsigned short* aptr[4];
#pragma unroll
  for (int i = 0; i < 4; ++i)
    aptr[i] = Xb + (size_t)(m0 + i * 32 + wrow) * DIM + swz;
  const unsigned short* gptr[2];
  const unsigned short* uptr[2];
#pragma unroll
  for (int i = 0; i < 2; ++i) {
    gptr[i] = Wg + (size_t)(n0 + i * 32 + wrow) * DIM + swz;
    uptr[i] = Wu + (size_t)(n0 + i * 32 + wrow) * DIM + swz;
  }
  f32x4 accg[4][2], accu[4][2];
#pragma unroll
  for (int mi = 0; mi < 4; ++mi)
#pragma unroll
    for (int ni = 0; ni < 2; ++ni) {
      accg[mi][ni] = {0.f, 0.f, 0.f, 0.f};
      accu[mi][ni] = {0.f, 0.f, 0.f, 0.f};
    }
  for (int k0 = 0; k0 < DIM; k0 += 64) {
    __syncthreads();
#pragma unroll
    for (int i = 0; i < 4; ++i) gload16(aptr[i] + k0, &As[i * 2048 + tid * 8]);
#pragma unroll
    for (int i = 0; i < 2; ++i) {
      gload16(gptr[i] + k0, &Bgs[i * 2048 + tid * 8]);
      gload16(uptr[i] + k0, &Bus[i * 2048 + tid * 8]);
    }
    __syncthreads();
#pragma unroll
    for (int h = 0; h < 2; ++h) {
      const int go = ((h * 4 + q) ^ cx) * 8;
      bf16x8 a[4], bg[2], bu[2];
#pragma unroll
      for (int mi = 0; mi < 4; ++mi)
        a[mi] = *(const bf16x8*)&As[(wm + mi * 16 + c) * 64 + go];
#pragma unroll
      for (int ni = 0; ni < 2; ++ni) {
        bg[ni] = *(const bf16x8*)&Bgs[(wn + ni * 16 + c) * 64 + go];
        bu[ni] = *(const bf16x8*)&Bus[(wn + ni * 16 + c) * 64 + go];
      }
#pragma unroll
      for (int mi = 0; mi < 4; ++mi)
#pragma unroll
        for (int ni = 0; ni < 2; ++ni) {
          accg[mi][ni] = __builtin_amdgcn_mfma_f32_16x16x32_bf16(a[mi], bg[ni], accg[mi][ni], 0, 0, 0);
          accu[mi][ni] = __builtin_amdgcn_mfma_f32_16x16x32_bf16(a[mi], bu[ni], accu[mi][ni], 0, 0, 0);
        }
    }
  }
#pragma unroll
  for (int mi = 0; mi < 4; ++mi)
#pragma unroll
    for (int ni = 0; ni < 2; ++ni)
#pragma unroll
      for (int r = 0; r < 4; ++r) {
        int row = wm + mi * 16 + q * 4 + r;
        int col = wn + ni * 16 + c;
        float g = accg[mi][ni][r];
        float u = accu[mi][ni][r];
        float h = (g / (1.f + __expf(-g))) * u;
        H[(size_t)(m0 + row) * HID + n0 + col] = f2b(h);
      }
}

// ---------------- merged sparse fused gate+up: all experts, one launch ----------------
__global__ __launch_bounds__(256, 2) void gateup_sparse_all_kernel(
    const unsigned short* __restrict__ Xb,
    const unsigned short* __restrict__ WguR,   // routed expert 0 base
    const int* __restrict__ tok, const float* __restrict__ wgt,
    const int* __restrict__ meta,
    unsigned short* __restrict__ H)
{
  const int yb = blockIdx.y;
  if (yb >= meta[15]) return;
  const int bm = meta[16 + yb];
  const int e = bm & 7, mb = bm >> 3;
  const int cnt = meta[e];
  const int pofs = meta[8 + e];
  const unsigned short* Wgu = WguR + (size_t)e * (2 * (size_t)HID * DIM);
  __shared__ __align__(16) unsigned short As[128 * 64];
  __shared__ __align__(16) unsigned short Bgs[64 * 64];
  __shared__ __align__(16) unsigned short Bus[64 * 64];
  __shared__ float wl[128];
  const int n0 = blockIdx.x * 64;
  const int tid = threadIdx.x;
  const int lane = tid & 63;
  const int w = tid >> 6;
  const int wm = (w & 1) * 64;
  const int wn = (w >> 1) * 32;
  const int c = lane & 15;
  const int q = lane >> 4;
  const int cx = c & 7;
  if (tid < 128)
    wl[tid] = (mb * 128 + tid < cnt) ? wgt[pofs + mb * 128 + tid] : 0.f;
  const unsigned short* Wg = Wgu;
  const unsigned short* Wu = Wgu + (size_t)HID * DIM;
  const int r8 = lane >> 3;
  const int swz = ((lane & 7) ^ r8) * 8;
  const int wrow = w * 8 + r8;
  const unsigned short* aptr[4];
#pragma unroll
  for (int i = 0; i < 4; ++i) {
    int s = mb * 128 + i * 32 + wrow;
    int t = (s < cnt) ? tok[pofs + s] : 0;
    aptr[i] = Xb + (size_t)t * DIM + swz;
  }
  const unsigned short* gptr[2];
  const unsigned short* uptr[2];
#pragma unroll
  for (int i = 0; i < 2; ++i) {
    gptr[i] = Wg + (size_t)(n0 + i * 32 + wrow) * DIM + swz;
    uptr[i] = Wu + (size_t)(n0 + i * 32 + wrow) * DIM + swz;
  }
  f32x4 accg[4][2], accu[4][2];
#pragma unroll
  for (int mi = 0; mi < 4; ++mi)
#pragma unroll
    for (int ni = 0; ni < 2; ++ni) {
      accg[mi][ni] = {0.f, 0.f, 0.f, 0.f};
      accu[mi][ni] = {0.f, 0.f, 0.f, 0.f};
    }
  for (int k0 = 0; k0 < DIM; k0 += 64) {
    __syncthreads();
#pragma unroll
    for (int i = 0; i < 4; ++i) gload16(aptr[i] + k0, &As[i * 2048 + tid * 8]);
#pragma unroll
    for (int i = 0; i < 2; ++i) {
      gload16(gptr[i] + k0, &Bgs[i * 2048 + tid * 8]);
      gload16(uptr[i] + k0, &Bus[i * 2048 + tid * 8]);
    }
    __syncthreads();
#pragma unroll
    for (int h = 0; h < 2; ++h) {
      const int go = ((h * 4 + q) ^ cx) * 8;
      bf16x8 a[4], bg[2], bu[2];
#pragma unroll
      for (int mi = 0; mi < 4; ++mi)
        a[mi] = *(const bf16x8*)&As[(wm + mi * 16 + c) * 64 + go];
#pragma unroll
      for (int ni = 0; ni < 2; ++ni) {
        bg[ni] = *(const bf16x8*)&Bgs[(wn + ni * 16 + c) * 64 + go];
        bu[ni] = *(const bf16x8*)&Bus[(wn + ni * 16 + c) * 64 + go];
      }
#pragma unroll
      for (int mi = 0; mi < 4; ++mi)
#pragma unroll
        for (int ni = 0; ni < 2; ++ni) {
          accg[mi][ni] = __builtin_amdgcn_mfma_f32_16x16x32_bf16(a[mi], bg[ni], accg[mi][ni], 0, 0, 0);
          accu[mi][ni] = __builtin_amdgcn_mfma_f32_16x16x32_bf16(a[mi], bu[ni], accu[mi][ni], 0, 0, 0);
        }
    }
  }
#pragma unroll
  for (int mi = 0; mi < 4; ++mi)
#pragma unroll
    for (int ni = 0; ni < 2; ++ni)
#pragma unroll
      for (int r = 0; r < 4; ++r) {
        int row = wm + mi * 16 + q * 4 + r;
        int col = wn + ni * 16 + c;
        float g = accg[mi][ni][r];
        float u = accu[mi][ni][r];
        float h = (g / (1.f + __expf(-g))) * u * wl[row];
        H[(size_t)(pofs + mb * 128 + row) * HID + n0 + col] = f2b(h);
      }
}

// ---------------- dense down (shared expert, initializes out) ----------------
__global__ __launch_bounds__(256, 2) void down_dense_kernel(
    const unsigned short* __restrict__ Hm,
    const unsigned short* __restrict__ WdT,
    float* __restrict__ out)
{
  __shared__ __align__(16) unsigned short As[128 * 64];
  __shared__ __align__(16) unsigned short Bs[128 * 64];
  const int m0 = blockIdx.y * 128;
  const int n0 = blockIdx.x * 128;
  const int tid = threadIdx.x;
  const int lane = tid & 63;
  const int w4 = tid >> 6;
  const int wm = (w4 & 1) * 64;
  const int wn = (w4 >> 1) * 64;
  const int c = lane & 15;
  const int q = lane >> 4;
  const int cx = c & 7;
  const int r8 = lane >> 3;
  const int swz = ((lane & 7) ^ r8) * 8;
  const int wrow = w4 * 8 + r8;
  const unsigned short* aptr[4];
  const unsigned short* bptr[4];
#pragma unroll
  for (int i = 0; i < 4; ++i) {
    aptr[i] = Hm + (size_t)(m0 + i * 32 + wrow) * HID + swz;
    bptr[i] = WdT + (size_t)(n0 + i * 32 + wrow) * HID + swz;
  }
  f32x4 acc[4][4];
#pragma unroll
  for (int mi = 0; mi < 4; ++mi)
#pragma unroll
    for (int ni = 0; ni < 4; ++ni) acc[mi][ni] = {0.f, 0.f, 0.f, 0.f};
  for (int k0 = 0; k0 < HID; k0 += 64) {
    __syncthreads();
#pragma unroll
    for (int i = 0; i < 4; ++i) {
      gload16(aptr[i] + k0, &As[i * 2048 + tid * 8]);
      gload16(bptr[i] + k0, &Bs[i * 2048 + tid * 8]);
    }
    __syncthreads();
#pragma unroll
    for (int h = 0; h < 2; ++h) {
      const int go = ((h * 4 + q) ^ cx) * 8;
      bf16x8 a[4], bb[4];
#pragma unroll
      for (int mi = 0; mi < 4; ++mi)
        a[mi] = *(const bf16x8*)&As[(wm + mi * 16 + c) * 64 + go];
#pragma unroll
      for (int ni = 0; ni < 4; ++ni)
        bb[ni] = *(const bf16x8*)&Bs[(wn + ni * 16 + c) * 64 + go];
#pragma unroll
      for (int mi = 0; mi < 4; ++mi)
#pragma unroll
        for (int ni = 0; ni < 4; ++ni)
          acc[mi][ni] = __builtin_amdgcn_mfma_f32_16x16x32_bf16(a[mi], bb[ni], acc[mi][ni], 0, 0, 0);
    }
  }
#pragma unroll
  for (int mi = 0; mi < 4; ++mi)
#pragma unroll
    for (int r = 0; r < 4; ++r) {
      int trow = m0 + wm + mi * 16 + q * 4 + r;
#pragma unroll
      for (int ni = 0; ni < 4; ++ni) {
        int col = n0 + wn + ni * 16 + c;
        out[(size_t)trow * DIM + col] = acc[mi][ni][r];
      }
    }
}

// ---------------- merged sparse down: all experts, split-K=2, atomic scatter ----------------
__global__ __launch_bounds__(256, 2) void down_sparse_all_kernel(
    const unsigned short* __restrict__ Hm,
    const unsigned short* __restrict__ WdR,    // routed expert 0 base
    const int* __restrict__ tok, const int* __restrict__ meta,
    float* __restrict__ out)
{
  const int yb = blockIdx.y;
  if (yb >= meta[15]) return;
  const int bm = meta[16 + yb];
  const int e = bm & 7, mb = bm >> 3;
  const int cnt = meta[e];
  const int pofs = meta[8 + e];
  const unsigned short* WdT = WdR + (size_t)e * ((size_t)HID * DIM);
  const int kbase = blockIdx.z * (HID / 2);
  __shared__ __align__(16) unsigned short As[128 * 64];
  __shared__ __align__(16) unsigned short Bs[128 * 64];
  __shared__ int tl[128];
  const int n0 = blockIdx.x * 128;
  const int tid = threadIdx.x;
  const int lane = tid & 63;
  const int w4 = tid >> 6;
  const int wm = (w4 & 1) * 64;
  const int wn = (w4 >> 1) * 64;
  const int c = lane & 15;
  const int q = lane >> 4;
  const int cx = c & 7;
  if (tid < 128)
    tl[tid] = (mb * 128 + tid < cnt) ? tok[pofs + mb * 128 + tid] : 0;
  const int r8 = lane >> 3;
  const int swz = ((lane & 7) ^ r8) * 8;
  const int wrow = w4 * 8 + r8;
  const unsigned short* aptr[4];
  const unsigned short* bptr[4];
#pragma unroll
  for (int i = 0; i < 4; ++i) {
    aptr[i] = Hm + (size_t)(pofs + mb * 128 + i * 32 + wrow) * HID + kbase + swz;
    bptr[i] = WdT + (size_t)(n0 + i * 32 + wrow) * HID + kbase + swz;
  }
  f32x4 acc[4][4];
#pragma unroll
  for (int mi = 0; mi < 4; ++mi)
#pragma unroll
    for (int ni = 0; ni < 4; ++ni) acc[mi][ni] = {0.f, 0.f, 0.f, 0.f};
  for (int k0 = 0; k0 < HID / 2; k0 += 64) {
    __syncthreads();
#pragma unroll
    for (int i = 0; i < 4; ++i) {
      gload16(aptr[i] + k0, &As[i * 2048 + tid * 8]);
      gload16(bptr[i] + k0, &Bs[i * 2048 + tid * 8]);
    }
    __syncthreads();
#pragma unroll
    for (int h = 0; h < 2; ++h) {
      const int go = ((h * 4 + q) ^ cx) * 8;
      bf16x8 a[4], bb[4];
#pragma unroll
      for (int mi = 0; mi < 4; ++mi)
        a[mi] = *(const bf16x8*)&As[(wm + mi * 16 + c) * 64 + go];
#pragma unroll
      for (int ni = 0; ni < 4; ++ni)
        bb[ni] = *(const bf16x8*)&Bs[(wn + ni * 16 + c) * 64 + go];
#pragma unroll
      for (int mi = 0; mi < 4; ++mi)
#pragma unroll
        for (int ni = 0; ni < 4; ++ni)
          acc[mi][ni] = __builtin_amdgcn_mfma_f32_16x16x32_bf16(a[mi], bb[ni], acc[mi][ni], 0, 0, 0);
    }
  }
#pragma unroll
  for (int mi = 0; mi < 4; ++mi)
#pragma unroll
    for (int r = 0; r < 4; ++r) {
      int lr = wm + mi * 16 + q * 4 + r;
      if (mb * 128 + lr < cnt) {
        int t = tl[lr];
#pragma unroll
        for (int ni = 0; ni < 4; ++ni) {
          int col = n0 + wn + ni * 16 + c;
          atomicAdd(&out[(size_t)t * DIM + col], acc[mi][ni][r]);
        }
      }
    }
}

extern "C" void kernel_launch(void* const* d_in, const int* in_sizes, int n_in,
                              void* d_out, int out_size, void* d_ws, size_t ws_size,
                              hipStream_t stream) {
  (void)in_sizes; (void)n_in; (void)out_size; (void)ws_size;
  const float* x   = (const float*)d_in[0];
  const float* sg  = (const float*)d_in[1];
  const float* su  = (const float*)d_in[2];
  const float* sd  = (const float*)d_in[3];
  const float* rg  = (const float*)d_in[4];
  const float* ru  = (const float*)d_in[5];
  const float* rd  = (const float*)d_in[6];
  const float* wrr = (const float*)d_in[7];
  const float* rb  = (const float*)d_in[8];
  float* out = (float*)d_out;

  char* ws = (char*)d_ws;
  dim3 blk(256);

  // -------- R2-proven schedule + fused router/xcvt --------
  unsigned short* Xb   = (unsigned short*)(ws + MW_XB);
  unsigned short* H    = (unsigned short*)(ws + MW_H);
  unsigned short* WguA = (unsigned short*)(ws + MW_WGU);
  unsigned short* WdA  = (unsigned short*)(ws + MW_WD);
  int*   tok           = (int*)(ws + MW_TOK);
  float* wgt           = (float*)(ws + MW_WGT);
  int*   meta          = (int*)(ws + MW_META);
  // eidx/ew parked inside H (consumed by build before any gateup writes H)
  int*   eidx = (int*)H;
  float* ew   = (float*)((char*)H + 32768);

  router_xcvt_kernel<<<dim3(TOKENS / 256), blk, 0, stream>>>(x, wrr, rb, Xb, eidx, ew);
  build_kernel<<<dim3(1), blk, 0, stream>>>(eidx, ew, tok, wgt, meta);
  transpose_all_kernel<<<dim3(8 * 2112), blk, 0, stream>>>(sg, su, sd, rg, ru, rd, WguA, WdA);

  gateup_kernel<<<dim3(HID / 64, TOKENS / 128), blk, 0, stream>>>(Xb, WguA, H);
  down_dense_kernel<<<dim3(DIM / 128, TOKENS / 128), blk, 0, stream>>>(H, WdA, out);

  const unsigned short* WguRt = WguA + 2 * (size_t)HID * DIM;   // routed slot base
  const unsigned short* WdRt  = WdA + (size_t)HID * DIM;
  gateup_sparse_all_kernel<<<dim3(HID / 64, 135), blk, 0, stream>>>(Xb, WguRt, tok, wgt, meta, H);
  down_sparse_all_kernel<<<dim3(DIM / 128, 135, 2), blk, 0, stream>>>(H, WdRt, tok, meta, out);
}